// Round 8
// baseline (241.208 us; speedup 1.0000x reference)
//
#include <hip/hip_runtime.h>
#include <math.h>
#include <stdint.h>

// TreeLSTM, 32 complete binary trees depth 10, heap order, d=128.
// R13: fused5L was VALU/trans bound at 1 block/CU (129.5KB LDS, Occ 18.6%,
//      VALU 44%). Buffers have nested lifetimes -> alias into a 64KB pool:
//      FLS->C9; HA->{H9,H8,H7}; CA->{C8,C7,C6,H6}. 2 blocks/CU (bounds
//      (512,4) pins VGPR=128, today's natural count). One new barrier after
//      level-A matvec (H9 aliases HA). Also: CA float4 writes were 8-way
//      bank conflicts -> 16B-chunk XOR swizzle ((row&7)<<2), and all c
//      buffers get float-level XOR (2-way both sides = free).

#define NTREES 32
#define MTREE 2047
#define NNODES (NTREES * MTREE)   // 65504

typedef __attribute__((ext_vector_type(8))) short bf16x8;
typedef __attribute__((ext_vector_type(4))) float f32x4;

__device__ __forceinline__ float sigmoidf_(float x) {
    return 1.0f / (1.0f + __expf(-x));
}
__device__ __forceinline__ float tanhf_(float x) {
    x = fminf(fmaxf(x, -10.0f), 10.0f);
    float e = __expf(2.0f * x);
    return (e - 1.0f) / (e + 1.0f);
}
__device__ __forceinline__ float bf2f(uint16_t b) {
    union { uint32_t u; float f; } v; v.u = ((uint32_t)b) << 16; return v.f;
}
// HW packed f32->bf16 (RNE), 1 instr per pair
__device__ __forceinline__ uint32_t cvtpk(float lo, float hi) {
    uint32_t r;
    asm("v_cvt_pk_bf16_f32 %0, %1, %2" : "=v"(r) : "v"(lo), "v"(hi));
    return r;
}
__device__ __forceinline__ uint16_t f2bf1(float f) {
    return (uint16_t)cvtpk(f, f);
}
__device__ __forceinline__ uint4 pack_bf8(float4 a, float4 b) {
    uint4 r;
    r.x = cvtpk(a.x, a.y); r.y = cvtpk(a.z, a.w);
    r.z = cvtpk(b.x, b.y); r.w = cvtpk(b.z, b.w);
    return r;
}

// raw workgroup barrier: LDS visibility only; global loads/stores stay in flight
__device__ __forceinline__ void lds_barrier() {
    asm volatile("s_waitcnt lgkmcnt(0)" ::: "memory");
    __builtin_amdgcn_s_barrier();
    __builtin_amdgcn_sched_barrier(0);
}

// Swizzled LDS layout: bf16 rows of 128 (16 chunks of 16B), XOR by row&7.
#define SWZ(row, chunk) ((row) * 128 + (((chunk) ^ ((row) & 7)) * 8))
// f32 scalar c-buffer: rows of 128 floats, float-level XOR (free R+W)
#define CIDX(row, col) ((row) * 128 + ((col) ^ (((row) & 7) << 2)))
// f32 buffer with float4 writes: 16B-chunk XOR by (row&7)<<2 (writes free)
#define CAX(row, col) ((row) * 128 + (((((col) >> 2) ^ (((row) & 7) << 2)) & 31) << 2) + ((col) & 3))

// parent h write into swizzled bf16 LDS row
__device__ __forceinline__ void hwr(uint16_t* buf, int row, int colf, float v) {
    buf[row * 128 + (((colf >> 3) ^ (row & 7)) * 8) + (colf & 7)] = f2bf1(v);
}

__device__ __forceinline__ void wx_unpack(ushort4 g, float o[4]) {
    o[0] = bf2f(g.x); o[1] = bf2f(g.y); o[2] = bf2f(g.z); o[3] = bf2f(g.w);
}

// full gate epilogue for one 16-child tile
__device__ __forceinline__ void gate_epi(const f32x4 acc[4], const float wxj[2][4],
                                         const float cch[4], float hv[2], float cn[2]) {
    float fc[4];
#pragma unroll
    for (int r = 0; r < 4; ++r)
        fc[r] = sigmoidf_(acc[3][r] + wxj[r >> 1][3]) * cch[r];
#pragma unroll
    for (int j = 0; j < 2; ++j) {
        float ip = acc[0][2 * j] + acc[0][2 * j + 1] + wxj[j][0];
        float op = acc[1][2 * j] + acc[1][2 * j + 1] + wxj[j][1];
        float up = acc[2][2 * j] + acc[2][2 * j + 1] + wxj[j][2];
        cn[j] = sigmoidf_(ip) * tanhf_(up) + fc[2 * j] + fc[2 * j + 1];
        hv[j] = sigmoidf_(op) * tanhf_(cn[j]);
    }
}

// ---------------------------------------------------------------------------
__global__ __launch_bounds__(128) void prep_k(const float* __restrict__ Wiou,
                                              const float* __restrict__ Wf,
                                              const float* __restrict__ Uiou,
                                              const float* __restrict__ Uf,
                                              const float* __restrict__ biou,
                                              const float* __restrict__ bf,
                                              uint16_t* __restrict__ WT,
                                              uint16_t* __restrict__ UT,
                                              float* __restrict__ biasS) {
    int n = blockIdx.x, k = threadIdx.x;
    if (n < 512) {
        WT[n * 128 + k] = f2bf1(n < 384 ? Wiou[k * 384 + n] : Wf[k * 128 + (n - 384)]);
    } else if (n < 1024) {
        int m = n - 512;
        UT[m * 128 + k] = f2bf1(m < 384 ? Uiou[k * 384 + m] : Uf[k * 128 + (m - 384)]);
    } else {
#pragma unroll
        for (int r = 0; r < 4; ++r) {
            int j = r * 128 + k;
            biasS[j] = j < 384 ? biou[j] : bf[j - 384];
        }
    }
}

// ---------------------------------------------------------------------------
// GEMM for INTERNAL nodes only: wx[v*512 + col*4 + gate] (bias included).
__global__ __launch_bounds__(512, 2) void gemm_int_k(const float* __restrict__ F,
                                                     const uint16_t* __restrict__ WT,
                                                     const float* __restrict__ biasS,
                                                     uint16_t* __restrict__ wx) {
    __shared__ uint16_t Fs[64 * 128];
    const int tid = threadIdx.x;
    const int w = tid >> 6, lane = tid & 63, q = lane >> 4, l15 = lane & 15;
    const int tree = blockIdx.x >> 4;
    const int j0 = (blockIdx.x & 15) * 64;
    const int vb = tree * MTREE;
    const int srow = tid >> 4, scx = tid & 15;

    int ja = j0 + srow;      ja = ja > 1022 ? 1022 : ja;
    int jb = j0 + 32 + srow; jb = jb > 1022 ? 1022 : jb;
    const float* sa = F + (size_t)(vb + ja) * 128 + scx * 8;
    const float* sb = F + (size_t)(vb + jb) * 128 + scx * 8;
    float4 a0 = *(const float4*)sa, a1 = *(const float4*)(sa + 4);
    float4 b0 = *(const float4*)sb, b1 = *(const float4*)(sb + 4);

    bf16x8 aW[4][4];
    float4 bias4[4];
#pragma unroll
    for (int s = 0; s < 4; ++s) {
        int row = (w + s * 8) * 16 + l15;
#pragma unroll
        for (int kc = 0; kc < 4; ++kc)
            aW[s][kc] = *(const bf16x8*)(WT + (size_t)row * 128 + kc * 32 + q * 8);
        bias4[s] = *(const float4*)(biasS + (w + s * 8) * 16 + q * 4);
    }

    *(uint4*)&Fs[SWZ(srow, scx)]      = pack_bf8(a0, a1);
    *(uint4*)&Fs[SWZ(32 + srow, scx)] = pack_bf8(b0, b1);
    lds_barrier();

#pragma unroll
    for (int nt = 0; nt < 4; ++nt) {
        bf16x8 b[4];
#pragma unroll
        for (int kc = 0; kc < 4; ++kc)
            b[kc] = *(const bf16x8*)&Fs[SWZ(nt * 16 + l15, kc * 4 + q)];
        f32x4 acc[4] = {};
#pragma unroll
        for (int s = 0; s < 4; ++s)
#pragma unroll
            for (int kc = 0; kc < 4; ++kc)
                acc[s] = __builtin_amdgcn_mfma_f32_16x16x32_bf16(aW[s][kc], b[kc], acc[s], 0, 0, 0);

        int j = j0 + nt * 16 + l15;
        float pi[4], po[4], pu[4], pf[4];
#pragma unroll
        for (int r = 0; r < 4; ++r) {
            pi[r] = acc[0][r] + bias4[0][r];
            po[r] = acc[1][r] + bias4[1][r];
            pu[r] = acc[2][r] + bias4[2][r];
            pf[r] = acc[3][r] + bias4[3][r];
        }
        int colb = w * 16 + q * 4;
        if (j < 1023) {
            uint4 w0, w1;
            w0.x = cvtpk(pi[0], po[0]);
            w0.y = cvtpk(pu[0], pf[0]);
            w0.z = cvtpk(pi[1], po[1]);
            w0.w = cvtpk(pu[1], pf[1]);
            w1.x = cvtpk(pi[2], po[2]);
            w1.y = cvtpk(pu[2], pf[2]);
            w1.z = cvtpk(pi[3], po[3]);
            w1.w = cvtpk(pu[3], pf[3]);
            uint16_t* wr = wx + (size_t)(vb + j) * 512 + colb * 4;
            *(uint4*)(wr) = w0;
            *(uint4*)(wr + 8) = w1;
        }
    }
}

// ---------------------------------------------------------------------------
__device__ __forceinline__ void load_bU(const uint16_t* __restrict__ UT, bf16x8 bU[4][4]) {
    const int tid = threadIdx.x;
    const int w = tid >> 6, lane = tid & 63, q = lane >> 4, l15 = lane & 15;
#pragma unroll
    for (int s = 0; s < 4; ++s) {
        int row = (w + s * 8) * 16 + l15;
#pragma unroll
        for (int kc = 0; kc < 4; ++kc)
            bU[s][kc] = *(const bf16x8*)(UT + (size_t)row * 128 + kc * 32 + q * 8);
    }
}

template<int NCT>
__device__ __forceinline__ void matvec_lds(const uint16_t* __restrict__ H,
                                           const bf16x8 bU[4][4],
                                           f32x4 acc[NCT][4], int l15, int q) {
#pragma unroll
    for (int ct = 0; ct < NCT; ++ct) {
        bf16x8 a[4];
#pragma unroll
        for (int kc = 0; kc < 4; ++kc)
            a[kc] = *(const bf16x8*)&H[SWZ(ct * 16 + l15, kc * 4 + q)];
#pragma unroll
        for (int s = 0; s < 4; ++s)
#pragma unroll
            for (int kc = 0; kc < 4; ++kc)
                acc[ct][s] = __builtin_amdgcn_mfma_f32_16x16x32_bf16(a[kc], bU[s][kc], acc[ct][s], 0, 0, 0);
    }
}

// ---------------------------------------------------------------------------
// Fused LEAF GEMM + depth-9..5 climb, 64KB aliased LDS pool -> 2 blocks/CU.
// Pool lifetimes: [0,16K) FLS -> C9 ; [16K,32K) HA -> H9|H8|H7 ;
// [32K,64K) CA -> C8|C7|C6|H6.
__global__ __launch_bounds__(512, 4) void fused5L_k(const float* __restrict__ F,
                                                    const uint16_t* __restrict__ WT,
                                                    const float* __restrict__ biasS,
                                                    const uint16_t* __restrict__ wx,
                                                    const uint16_t* __restrict__ UT,
                                                    float* __restrict__ h,
                                                    float* __restrict__ c) {
    __shared__ __align__(16) char SM[65536];
    uint16_t* FLS = (uint16_t*)SM;              // [0, 16K)   phase1
    float*    C9v = (float*)SM;                 // [0, 16K)   A-epi .. B-epi
    uint16_t* HA  = (uint16_t*)(SM + 16384);    // [16K, 32K) phase1 .. A-matvec
    uint16_t* H9  = (uint16_t*)(SM + 16384);    // 8K  A-epi .. B-matvec
    uint16_t* H8  = (uint16_t*)(SM + 24576);    // 4K  B-epi .. C-matvec
    uint16_t* H7  = (uint16_t*)(SM + 28672);    // 4K  C-epi .. D-matvec
    float*    CA  = (float*)(SM + 32768);       // 32K phase1 .. A-epi
    float*    C8  = (float*)(SM + 32768);       // 8K  B-epi .. C-epi
    float*    C7  = (float*)(SM + 40960);       // 8K  C-epi .. D-epi
    float*    C6  = (float*)(SM + 49152);       // 8K  D-epi .. E-epi
    uint16_t* H6  = (uint16_t*)(SM + 57344);    // 4K  D-epi .. E-matvec

    const int tid = threadIdx.x;
    const int w = tid >> 6, lane = tid & 63, q = lane >> 4, l15 = lane & 15;
    const int colf = w * 16 + l15;
    const int tree = blockIdx.x >> 4;
    const int pos5 = (blockIdx.x & 15) * 2;
    const int vbase = tree * MTREE;
    const int v5 = vbase + 31 + pos5;
    const int v6 = vbase + 63 + 2 * pos5;
    const int v7 = vbase + 127 + 4 * pos5;
    const int v8 = vbase + 255 + 8 * pos5;
    const int v9 = vbase + 511 + 16 * pos5;
    const int vL = vbase + 1023 + 32 * pos5;

    // (1) staging loads FIRST: 64 leaf feature rows
    const int srow = tid >> 4, scx = tid & 15;
    const float* sa = F + (size_t)(vL + srow) * 128 + scx * 8;
    const float* sb = F + (size_t)(vL + 32 + srow) * 128 + scx * 8;
    float4 a0 = *(const float4*)sa, a1 = *(const float4*)(sa + 4);
    float4 b0 = *(const float4*)sb, b1 = *(const float4*)(sb + 4);

    // (2) W weights + bias (L2-warm)
    bf16x8 aW[4][4];
    float4 bias4[4];
#pragma unroll
    for (int s = 0; s < 4; ++s) {
        int row = (w + s * 8) * 16 + l15;
#pragma unroll
        for (int kc = 0; kc < 4; ++kc)
            aW[s][kc] = *(const bf16x8*)(WT + (size_t)row * 128 + kc * 32 + q * 8);
        bias4[s] = *(const float4*)(biasS + (w + s * 8) * 16 + q * 4);
    }

    // (3) scattered wx prefetch for d9/d8
    float wxA[4][2][4], wxB[2][2][4];
#pragma unroll
    for (int ct = 0; ct < 4; ++ct)
#pragma unroll
        for (int j = 0; j < 2; ++j) {
            int pl = ct * 8 + q * 2 + j;
            wx_unpack(*(const ushort4*)(wx + (size_t)(v9 + pl) * 512 + colf * 4), wxA[ct][j]);
        }
#pragma unroll
    for (int ct = 0; ct < 2; ++ct)
#pragma unroll
        for (int j = 0; j < 2; ++j) {
            int pl = ct * 8 + q * 2 + j;
            wx_unpack(*(const ushort4*)(wx + (size_t)(v8 + pl) * 512 + colf * 4), wxB[ct][j]);
        }

    // (4) pack F -> LDS
    *(uint4*)&FLS[SWZ(srow, scx)]      = pack_bf8(a0, a1);
    *(uint4*)&FLS[SWZ(32 + srow, scx)] = pack_bf8(b0, b1);
    lds_barrier();

    // ---- Phase 1: leaf GEMM + leaf epilogue ----
#pragma unroll
    for (int nt = 0; nt < 4; ++nt) {
        bf16x8 b[4];
#pragma unroll
        for (int kc = 0; kc < 4; ++kc)
            b[kc] = *(const bf16x8*)&FLS[SWZ(nt * 16 + l15, kc * 4 + q)];
        f32x4 acc[4] = {};
#pragma unroll
        for (int s = 0; s < 4; ++s)
#pragma unroll
            for (int kc = 0; kc < 4; ++kc)
                acc[s] = __builtin_amdgcn_mfma_f32_16x16x32_bf16(aW[s][kc], b[kc], acc[s], 0, 0, 0);

        int row = nt * 16 + l15;
        int colb = w * 16 + q * 4;
        float cv[4], hv[4];
#pragma unroll
        for (int r = 0; r < 4; ++r) {
            float pi = acc[0][r] + bias4[0][r];
            float po = acc[1][r] + bias4[1][r];
            float pu = acc[2][r] + bias4[2][r];
            float cn = sigmoidf_(pi) * tanhf_(pu);
            cv[r] = cn;
            hv[r] = sigmoidf_(po) * tanhf_(cn);
        }
        *(float4*)&h[(size_t)(vL + row) * 128 + colb] = *(float4*)hv;
        int chunk = colb >> 3, within = colb & 7;
        uint2 hp;
        hp.x = cvtpk(hv[0], hv[1]);
        hp.y = cvtpk(hv[2], hv[3]);
        *(uint2*)&HA[row * 128 + ((chunk ^ (row & 7)) * 8) + within] = hp;
        *(float4*)&CA[CAX(row, colb)] = *(float4*)cv;
    }
    bf16x8 bU[4][4];
    load_bU(UT, bU);    // after aW's last use
    lds_barrier();

    // ---- LEVEL A (d9): 32 parents from 64 leaf children ----
    float wxC[2][4], wxD[2][4], wxE[2][4];
    {
        f32x4 acc[4][4] = {};
        matvec_lds<4>(HA, bU, acc, l15, q);
        // prefetch deeper-level wx
#pragma unroll
        for (int j = 0; j < 2; ++j) {
            int pl = q * 2 + j;
            wx_unpack(*(const ushort4*)(wx + (size_t)(v7 + pl) * 512 + colf * 4), wxC[j]);
            wx_unpack(*(const ushort4*)(wx + (size_t)(v6 + pl) * 512 + colf * 4), wxD[j]);
            wx_unpack(*(const ushort4*)(wx + (size_t)(v5 + pl) * 512 + colf * 4), wxE[j]);
        }
        // HA fully consumed by all waves before H9 (aliasing HA) is written
        lds_barrier();
#pragma unroll
        for (int ct = 0; ct < 4; ++ct) {
            float cch[4];
#pragma unroll
            for (int r = 0; r < 4; ++r)
                cch[r] = CA[CAX(ct * 16 + q * 4 + r, colf)];
            float hv[2], cn[2];
            gate_epi(acc[ct], wxA[ct], cch, hv, cn);
#pragma unroll
            for (int j = 0; j < 2; ++j) {
                int pl = ct * 8 + q * 2 + j;
                h[(size_t)(v9 + pl) * 128 + colf] = hv[j];
                hwr(H9, pl, colf, hv[j]);
                C9v[CIDX(pl, colf)] = cn[j];
            }
        }
    }
    lds_barrier();

    // ---- LEVEL B (d8): 16 parents ----
    {
        float cch[2][4];
#pragma unroll
        for (int ct = 0; ct < 2; ++ct)
#pragma unroll
            for (int r = 0; r < 4; ++r)
                cch[ct][r] = C9v[CIDX(ct * 16 + q * 4 + r, colf)];
        f32x4 acc[2][4] = {};
        matvec_lds<2>(H9, bU, acc, l15, q);
#pragma unroll
        for (int ct = 0; ct < 2; ++ct) {
            float hv[2], cn[2];
            gate_epi(acc[ct], wxB[ct], cch[ct], hv, cn);
#pragma unroll
            for (int j = 0; j < 2; ++j) {
                int pl = ct * 8 + q * 2 + j;
                h[(size_t)(v8 + pl) * 128 + colf] = hv[j];
                hwr(H8, pl, colf, hv[j]);
                C8[CIDX(pl, colf)] = cn[j];
            }
        }
    }
    lds_barrier();

    // ---- LEVEL C (d7): 8 parents ----
    {
        float cch[4];
#pragma unroll
        for (int r = 0; r < 4; ++r)
            cch[r] = C8[CIDX(q * 4 + r, colf)];
        f32x4 acc[1][4] = {};
        matvec_lds<1>(H8, bU, acc, l15, q);
        float hv[2], cn[2];
        gate_epi(acc[0], wxC, cch, hv, cn);
#pragma unroll
        for (int j = 0; j < 2; ++j) {
            int pl = q * 2 + j;
            h[(size_t)(v7 + pl) * 128 + colf] = hv[j];
            hwr(H7, pl, colf, hv[j]);
            C7[CIDX(pl, colf)] = cn[j];
        }
    }
    lds_barrier();

    // ---- LEVEL D (d6): 4 parents ----
    {
        float cch[4];
#pragma unroll
        for (int r = 0; r < 4; ++r)
            cch[r] = C7[CIDX(q * 4 + r, colf)];
        f32x4 acc[1][4] = {};
        matvec_lds<1>(H7, bU, acc, l15, q);
        float hv[2], cn[2];
        gate_epi(acc[0], wxD, cch, hv, cn);
#pragma unroll
        for (int j = 0; j < 2; ++j) {
            int pl = q * 2 + j;
            if (pl < 4) {
                h[(size_t)(v6 + pl) * 128 + colf] = hv[j];
                hwr(H6, pl, colf, hv[j]);
                C6[CIDX(pl, colf)] = cn[j];
            }
        }
    }
    lds_barrier();

    // ---- LEVEL E (d5): 2 parents -> global h + c ----
    {
        float cch[4];
#pragma unroll
        for (int r = 0; r < 4; ++r)
            cch[r] = C6[CIDX(q * 4 + r, colf)];
        f32x4 acc[1][4] = {};
        matvec_lds<1>(H6, bU, acc, l15, q);
        float hv[2], cn[2];
        gate_epi(acc[0], wxE, cch, hv, cn);
#pragma unroll
        for (int j = 0; j < 2; ++j) {
            int pl = q * 2 + j;
            if (pl < 2) {
                h[(size_t)(v5 + pl) * 128 + colf] = hv[j];
                c[(size_t)(v5 + pl) * 128 + colf] = cn[j];
            }
        }
    }
}

// ---------------------------------------------------------------------------
// Tail: dep 4..0 (5 small groups), one block per tree. Unchanged from R12.
__global__ __launch_bounds__(512, 1) void tail_k(const uint16_t* __restrict__ wx,
                                                 const uint16_t* __restrict__ UT,
                                                 const float* __restrict__ cglob,
                                                 float* __restrict__ h) {
    __shared__ uint16_t Hbuf[48 * 128];   // 12 KB
    __shared__ float CS[32 * 132];        // 16.9 KB
    bf16x8 bU[4][4];
    load_bU(UT, bU);
    const int tree = blockIdx.x;
    const int tid = threadIdx.x;
    const int w = tid >> 6, lane = tid & 63, q = lane >> 4, l15 = lane & 15;
    const int colf = w * 16 + l15;
    const int vbase = tree * MTREE;

    const int srow = tid >> 4, scx = tid & 15;
    const float* ssrc = h + (size_t)(vbase + 31 + srow) * 128 + scx * 8;
    float4 s0 = *(const float4*)ssrc;
    float4 s1 = *(const float4*)(ssrc + 4);

    float wx0[2][2][4], wx1[2][4], wx2[2][4], wx3[2][4], wx4[2][4];
#pragma unroll
    for (int ct = 0; ct < 2; ++ct)
#pragma unroll
        for (int j = 0; j < 2; ++j) {
            int pl = ct * 8 + q * 2 + j;
            wx_unpack(*(const ushort4*)(wx + (size_t)(vbase + 15 + pl) * 512 + colf * 4), wx0[ct][j]);
        }
#pragma unroll
    for (int j = 0; j < 2; ++j) {
        int pl = q * 2 + j;
        wx_unpack(*(const ushort4*)(wx + (size_t)(vbase + 7 + pl) * 512 + colf * 4), wx1[j]);
        wx_unpack(*(const ushort4*)(wx + (size_t)(vbase + 3 + pl) * 512 + colf * 4), wx2[j]);
        wx_unpack(*(const ushort4*)(wx + (size_t)(vbase + 1 + pl) * 512 + colf * 4), wx3[j]);
        wx_unpack(*(const ushort4*)(wx + (size_t)(vbase + 0 + pl) * 512 + colf * 4), wx4[j]);
    }
    float cgl[2][4];
#pragma unroll
    for (int ct = 0; ct < 2; ++ct)
#pragma unroll
        for (int r = 0; r < 4; ++r) {
            int cl = ct * 16 + q * 4 + r;
            cgl[ct][r] = cglob[(size_t)(vbase + 31 + cl) * 128 + colf];
        }

    *(uint4*)&Hbuf[SWZ(srow, scx)] = pack_bf8(s0, s1);
    lds_barrier();

    // ---- G0: dep4, 16 parents
    {
        f32x4 acc[2][4] = {};
        matvec_lds<2>(Hbuf, bU, acc, l15, q);
#pragma unroll
        for (int ct = 0; ct < 2; ++ct) {
            float hv[2], cn[2];
            gate_epi(acc[ct], wx0[ct], cgl[ct], hv, cn);
#pragma unroll
            for (int j = 0; j < 2; ++j) {
                int pl = ct * 8 + q * 2 + j;
                h[(size_t)(vbase + 15 + pl) * 128 + colf] = hv[j];
                hwr(Hbuf, 32 + pl, colf, hv[j]);
                CS[pl * 132 + colf] = cn[j];
            }
        }
    }
    lds_barrier();

    // ---- G1: dep3, 8 parents
    {
        float cch[4];
#pragma unroll
        for (int r = 0; r < 4; ++r)
            cch[r] = CS[(q * 4 + r) * 132 + colf];
        f32x4 acc[1][4] = {};
        matvec_lds<1>(&Hbuf[32 * 128], bU, acc, l15, q);
        float hv[2], cn[2];
        gate_epi(acc[0], wx1, cch, hv, cn);
#pragma unroll
        for (int j = 0; j < 2; ++j) {
            int pl = q * 2 + j;
            h[(size_t)(vbase + 7 + pl) * 128 + colf] = hv[j];
            hwr(Hbuf, pl, colf, hv[j]);
            CS[(16 + pl) * 132 + colf] = cn[j];
        }
    }
    lds_barrier();

    // ---- G2: dep2, 4 parents
    {
        float cch[4];
#pragma unroll
        for (int r = 0; r < 4; ++r)
            cch[r] = CS[(16 + q * 4 + r) * 132 + colf];
        f32x4 acc[1][4] = {};
        matvec_lds<1>(Hbuf, bU, acc, l15, q);
        float hv[2], cn[2];
        gate_epi(acc[0], wx2, cch, hv, cn);
#pragma unroll
        for (int j = 0; j < 2; ++j) {
            int pl = q * 2 + j;
            if (pl < 4) {
                h[(size_t)(vbase + 3 + pl) * 128 + colf] = hv[j];
                hwr(Hbuf, 32 + pl, colf, hv[j]);
                CS[pl * 132 + colf] = cn[j];
            }
        }
    }
    lds_barrier();

    // ---- G3: dep1, 2 parents
    {
        float cch[4];
#pragma unroll
        for (int r = 0; r < 4; ++r)
            cch[r] = CS[(q * 4 + r) * 132 + colf];
        f32x4 acc[1][4] = {};
        matvec_lds<1>(&Hbuf[32 * 128], bU, acc, l15, q);
        float hv[2], cn[2];
        gate_epi(acc[0], wx3, cch, hv, cn);
#pragma unroll
        for (int j = 0; j < 2; ++j) {
            int pl = q * 2 + j;
            if (pl < 2) {
                h[(size_t)(vbase + 1 + pl) * 128 + colf] = hv[j];
                hwr(Hbuf, pl, colf, hv[j]);
                CS[(16 + pl) * 132 + colf] = cn[j];
            }
        }
    }
    lds_barrier();

    // ---- G4: dep0, root
    {
        float cch[4];
#pragma unroll
        for (int r = 0; r < 4; ++r)
            cch[r] = CS[(16 + q * 4 + r) * 132 + colf];
        f32x4 acc[1][4] = {};
        matvec_lds<1>(Hbuf, bU, acc, l15, q);
        float hv[2], cn[2];
        gate_epi(acc[0], wx4, cch, hv, cn);
        if (q == 0) {
            h[(size_t)vbase * 128 + colf] = hv[0];
        }
    }
}

// ---------------------------------------------------------------------------
extern "C" void kernel_launch(void* const* d_in, const int* in_sizes, int n_in,
                              void* d_out, int out_size, void* d_ws, size_t ws_size,
                              hipStream_t stream) {
    const float* features = (const float*)d_in[0];
    const float* W_iou    = (const float*)d_in[1];
    const float* b_iou    = (const float*)d_in[2];
    const float* U_iou    = (const float*)d_in[3];
    const float* W_f      = (const float*)d_in[4];
    const float* b_f      = (const float*)d_in[5];
    const float* U_f      = (const float*)d_in[6];
    float* h = (float*)d_out;

    char* wp = (char*)d_ws;
    uint16_t* wx    = (uint16_t*)wp; wp += (size_t)NNODES * 512 * 2;
    float*    c     = (float*)wp;    wp += (size_t)NNODES * 128 * 4;
    uint16_t* WT    = (uint16_t*)wp; wp += 512 * 128 * 2;
    uint16_t* UT    = (uint16_t*)wp; wp += 512 * 128 * 2;
    float*    biasS = (float*)wp;    wp += 512 * 4;

    hipLaunchKernelGGL(prep_k, dim3(1025), dim3(128), 0, stream,
                       W_iou, W_f, U_iou, U_f, b_iou, b_f, WT, UT, biasS);
    hipLaunchKernelGGL(gemm_int_k, dim3(512), dim3(512), 0, stream,
                       features, WT, biasS, wx);
    hipLaunchKernelGGL(fused5L_k, dim3(512), dim3(512), 0, stream,
                       features, WT, biasS, wx, UT, h, c);
    hipLaunchKernelGGL(tail_k, dim3(32), dim3(512), 0, stream, wx, UT, c, h);
}

// Round 9
// 168.544 us; speedup vs baseline: 1.4311x; 1.4311x over previous
//
#include <hip/hip_runtime.h>
#include <math.h>
#include <stdint.h>

// TreeLSTM, 32 complete binary trees depth 10, heap order, d=128.
// R14: R13's only bug was the launch_bounds clamp: (512,4) implied a 64-VGPR
//      budget < the kernel's natural 128 -> catastrophic scratch spill
//      (FETCH 129MB, WRITE 218MB, 121-169us). RULE (2nd offense): never set
//      min-waves so the implied VGPR budget < measured VGPR_Count.
//      Fix: (512,2). The 64KB aliased LDS pool (R13, correctness-proven)
//      already allows 2 blocks/CU at 128 VGPRs without any clamp.

#define NTREES 32
#define MTREE 2047
#define NNODES (NTREES * MTREE)   // 65504

typedef __attribute__((ext_vector_type(8))) short bf16x8;
typedef __attribute__((ext_vector_type(4))) float f32x4;

__device__ __forceinline__ float sigmoidf_(float x) {
    return 1.0f / (1.0f + __expf(-x));
}
__device__ __forceinline__ float tanhf_(float x) {
    x = fminf(fmaxf(x, -10.0f), 10.0f);
    float e = __expf(2.0f * x);
    return (e - 1.0f) / (e + 1.0f);
}
__device__ __forceinline__ float bf2f(uint16_t b) {
    union { uint32_t u; float f; } v; v.u = ((uint32_t)b) << 16; return v.f;
}
// HW packed f32->bf16 (RNE), 1 instr per pair
__device__ __forceinline__ uint32_t cvtpk(float lo, float hi) {
    uint32_t r;
    asm("v_cvt_pk_bf16_f32 %0, %1, %2" : "=v"(r) : "v"(lo), "v"(hi));
    return r;
}
__device__ __forceinline__ uint16_t f2bf1(float f) {
    return (uint16_t)cvtpk(f, f);
}
__device__ __forceinline__ uint4 pack_bf8(float4 a, float4 b) {
    uint4 r;
    r.x = cvtpk(a.x, a.y); r.y = cvtpk(a.z, a.w);
    r.z = cvtpk(b.x, b.y); r.w = cvtpk(b.z, b.w);
    return r;
}

// raw workgroup barrier: LDS visibility only; global loads/stores stay in flight
__device__ __forceinline__ void lds_barrier() {
    asm volatile("s_waitcnt lgkmcnt(0)" ::: "memory");
    __builtin_amdgcn_s_barrier();
    __builtin_amdgcn_sched_barrier(0);
}

// Swizzled LDS layout: bf16 rows of 128 (16 chunks of 16B), XOR by row&7.
#define SWZ(row, chunk) ((row) * 128 + (((chunk) ^ ((row) & 7)) * 8))
// f32 scalar c-buffer: rows of 128 floats, float-level XOR (free R+W)
#define CIDX(row, col) ((row) * 128 + ((col) ^ (((row) & 7) << 2)))
// f32 buffer with float4 writes: 16B-chunk XOR by (row&7)<<2 (writes free)
#define CAX(row, col) ((row) * 128 + (((((col) >> 2) ^ (((row) & 7) << 2)) & 31) << 2) + ((col) & 3))

// parent h write into swizzled bf16 LDS row
__device__ __forceinline__ void hwr(uint16_t* buf, int row, int colf, float v) {
    buf[row * 128 + (((colf >> 3) ^ (row & 7)) * 8) + (colf & 7)] = f2bf1(v);
}

__device__ __forceinline__ void wx_unpack(ushort4 g, float o[4]) {
    o[0] = bf2f(g.x); o[1] = bf2f(g.y); o[2] = bf2f(g.z); o[3] = bf2f(g.w);
}

// full gate epilogue for one 16-child tile
__device__ __forceinline__ void gate_epi(const f32x4 acc[4], const float wxj[2][4],
                                         const float cch[4], float hv[2], float cn[2]) {
    float fc[4];
#pragma unroll
    for (int r = 0; r < 4; ++r)
        fc[r] = sigmoidf_(acc[3][r] + wxj[r >> 1][3]) * cch[r];
#pragma unroll
    for (int j = 0; j < 2; ++j) {
        float ip = acc[0][2 * j] + acc[0][2 * j + 1] + wxj[j][0];
        float op = acc[1][2 * j] + acc[1][2 * j + 1] + wxj[j][1];
        float up = acc[2][2 * j] + acc[2][2 * j + 1] + wxj[j][2];
        cn[j] = sigmoidf_(ip) * tanhf_(up) + fc[2 * j] + fc[2 * j + 1];
        hv[j] = sigmoidf_(op) * tanhf_(cn[j]);
    }
}

// ---------------------------------------------------------------------------
__global__ __launch_bounds__(128) void prep_k(const float* __restrict__ Wiou,
                                              const float* __restrict__ Wf,
                                              const float* __restrict__ Uiou,
                                              const float* __restrict__ Uf,
                                              const float* __restrict__ biou,
                                              const float* __restrict__ bf,
                                              uint16_t* __restrict__ WT,
                                              uint16_t* __restrict__ UT,
                                              float* __restrict__ biasS) {
    int n = blockIdx.x, k = threadIdx.x;
    if (n < 512) {
        WT[n * 128 + k] = f2bf1(n < 384 ? Wiou[k * 384 + n] : Wf[k * 128 + (n - 384)]);
    } else if (n < 1024) {
        int m = n - 512;
        UT[m * 128 + k] = f2bf1(m < 384 ? Uiou[k * 384 + m] : Uf[k * 128 + (m - 384)]);
    } else {
#pragma unroll
        for (int r = 0; r < 4; ++r) {
            int j = r * 128 + k;
            biasS[j] = j < 384 ? biou[j] : bf[j - 384];
        }
    }
}

// ---------------------------------------------------------------------------
// GEMM for INTERNAL nodes only: wx[v*512 + col*4 + gate] (bias included).
__global__ __launch_bounds__(512, 2) void gemm_int_k(const float* __restrict__ F,
                                                     const uint16_t* __restrict__ WT,
                                                     const float* __restrict__ biasS,
                                                     uint16_t* __restrict__ wx) {
    __shared__ uint16_t Fs[64 * 128];
    const int tid = threadIdx.x;
    const int w = tid >> 6, lane = tid & 63, q = lane >> 4, l15 = lane & 15;
    const int tree = blockIdx.x >> 4;
    const int j0 = (blockIdx.x & 15) * 64;
    const int vb = tree * MTREE;
    const int srow = tid >> 4, scx = tid & 15;

    int ja = j0 + srow;      ja = ja > 1022 ? 1022 : ja;
    int jb = j0 + 32 + srow; jb = jb > 1022 ? 1022 : jb;
    const float* sa = F + (size_t)(vb + ja) * 128 + scx * 8;
    const float* sb = F + (size_t)(vb + jb) * 128 + scx * 8;
    float4 a0 = *(const float4*)sa, a1 = *(const float4*)(sa + 4);
    float4 b0 = *(const float4*)sb, b1 = *(const float4*)(sb + 4);

    bf16x8 aW[4][4];
    float4 bias4[4];
#pragma unroll
    for (int s = 0; s < 4; ++s) {
        int row = (w + s * 8) * 16 + l15;
#pragma unroll
        for (int kc = 0; kc < 4; ++kc)
            aW[s][kc] = *(const bf16x8*)(WT + (size_t)row * 128 + kc * 32 + q * 8);
        bias4[s] = *(const float4*)(biasS + (w + s * 8) * 16 + q * 4);
    }

    *(uint4*)&Fs[SWZ(srow, scx)]      = pack_bf8(a0, a1);
    *(uint4*)&Fs[SWZ(32 + srow, scx)] = pack_bf8(b0, b1);
    lds_barrier();

#pragma unroll
    for (int nt = 0; nt < 4; ++nt) {
        bf16x8 b[4];
#pragma unroll
        for (int kc = 0; kc < 4; ++kc)
            b[kc] = *(const bf16x8*)&Fs[SWZ(nt * 16 + l15, kc * 4 + q)];
        f32x4 acc[4] = {};
#pragma unroll
        for (int s = 0; s < 4; ++s)
#pragma unroll
            for (int kc = 0; kc < 4; ++kc)
                acc[s] = __builtin_amdgcn_mfma_f32_16x16x32_bf16(aW[s][kc], b[kc], acc[s], 0, 0, 0);

        int j = j0 + nt * 16 + l15;
        float pi[4], po[4], pu[4], pf[4];
#pragma unroll
        for (int r = 0; r < 4; ++r) {
            pi[r] = acc[0][r] + bias4[0][r];
            po[r] = acc[1][r] + bias4[1][r];
            pu[r] = acc[2][r] + bias4[2][r];
            pf[r] = acc[3][r] + bias4[3][r];
        }
        int colb = w * 16 + q * 4;
        if (j < 1023) {
            uint4 w0, w1;
            w0.x = cvtpk(pi[0], po[0]);
            w0.y = cvtpk(pu[0], pf[0]);
            w0.z = cvtpk(pi[1], po[1]);
            w0.w = cvtpk(pu[1], pf[1]);
            w1.x = cvtpk(pi[2], po[2]);
            w1.y = cvtpk(pu[2], pf[2]);
            w1.z = cvtpk(pi[3], po[3]);
            w1.w = cvtpk(pu[3], pf[3]);
            uint16_t* wr = wx + (size_t)(vb + j) * 512 + colb * 4;
            *(uint4*)(wr) = w0;
            *(uint4*)(wr + 8) = w1;
        }
    }
}

// ---------------------------------------------------------------------------
__device__ __forceinline__ void load_bU(const uint16_t* __restrict__ UT, bf16x8 bU[4][4]) {
    const int tid = threadIdx.x;
    const int w = tid >> 6, lane = tid & 63, q = lane >> 4, l15 = lane & 15;
#pragma unroll
    for (int s = 0; s < 4; ++s) {
        int row = (w + s * 8) * 16 + l15;
#pragma unroll
        for (int kc = 0; kc < 4; ++kc)
            bU[s][kc] = *(const bf16x8*)(UT + (size_t)row * 128 + kc * 32 + q * 8);
    }
}

template<int NCT>
__device__ __forceinline__ void matvec_lds(const uint16_t* __restrict__ H,
                                           const bf16x8 bU[4][4],
                                           f32x4 acc[NCT][4], int l15, int q) {
#pragma unroll
    for (int ct = 0; ct < NCT; ++ct) {
        bf16x8 a[4];
#pragma unroll
        for (int kc = 0; kc < 4; ++kc)
            a[kc] = *(const bf16x8*)&H[SWZ(ct * 16 + l15, kc * 4 + q)];
#pragma unroll
        for (int s = 0; s < 4; ++s)
#pragma unroll
            for (int kc = 0; kc < 4; ++kc)
                acc[ct][s] = __builtin_amdgcn_mfma_f32_16x16x32_bf16(a[kc], bU[s][kc], acc[ct][s], 0, 0, 0);
    }
}

// ---------------------------------------------------------------------------
// Fused LEAF GEMM + depth-9..5 climb, 64KB aliased LDS pool -> 2 blocks/CU.
// Pool lifetimes: [0,16K) FLS -> C9 ; [16K,32K) HA -> H9|H8|H7 ;
// [32K,64K) CA -> C8|C7|C6|H6.
__global__ __launch_bounds__(512, 2) void fused5L_k(const float* __restrict__ F,
                                                    const uint16_t* __restrict__ WT,
                                                    const float* __restrict__ biasS,
                                                    const uint16_t* __restrict__ wx,
                                                    const uint16_t* __restrict__ UT,
                                                    float* __restrict__ h,
                                                    float* __restrict__ c) {
    __shared__ __align__(16) char SM[65536];
    uint16_t* FLS = (uint16_t*)SM;              // [0, 16K)   phase1
    float*    C9v = (float*)SM;                 // [0, 16K)   A-epi .. B-epi
    uint16_t* HA  = (uint16_t*)(SM + 16384);    // [16K, 32K) phase1 .. A-matvec
    uint16_t* H9  = (uint16_t*)(SM + 16384);    // 8K  A-epi .. B-matvec
    uint16_t* H8  = (uint16_t*)(SM + 24576);    // 4K  B-epi .. C-matvec
    uint16_t* H7  = (uint16_t*)(SM + 28672);    // 4K  C-epi .. D-matvec
    float*    CA  = (float*)(SM + 32768);       // 32K phase1 .. A-epi
    float*    C8  = (float*)(SM + 32768);       // 8K  B-epi .. C-epi
    float*    C7  = (float*)(SM + 40960);       // 8K  C-epi .. D-epi
    float*    C6  = (float*)(SM + 49152);       // 8K  D-epi .. E-epi
    uint16_t* H6  = (uint16_t*)(SM + 57344);    // 4K  D-epi .. E-matvec

    const int tid = threadIdx.x;
    const int w = tid >> 6, lane = tid & 63, q = lane >> 4, l15 = lane & 15;
    const int colf = w * 16 + l15;
    const int tree = blockIdx.x >> 4;
    const int pos5 = (blockIdx.x & 15) * 2;
    const int vbase = tree * MTREE;
    const int v5 = vbase + 31 + pos5;
    const int v6 = vbase + 63 + 2 * pos5;
    const int v7 = vbase + 127 + 4 * pos5;
    const int v8 = vbase + 255 + 8 * pos5;
    const int v9 = vbase + 511 + 16 * pos5;
    const int vL = vbase + 1023 + 32 * pos5;

    // (1) staging loads FIRST: 64 leaf feature rows
    const int srow = tid >> 4, scx = tid & 15;
    const float* sa = F + (size_t)(vL + srow) * 128 + scx * 8;
    const float* sb = F + (size_t)(vL + 32 + srow) * 128 + scx * 8;
    float4 a0 = *(const float4*)sa, a1 = *(const float4*)(sa + 4);
    float4 b0 = *(const float4*)sb, b1 = *(const float4*)(sb + 4);

    // (2) W weights + bias (L2-warm)
    bf16x8 aW[4][4];
    float4 bias4[4];
#pragma unroll
    for (int s = 0; s < 4; ++s) {
        int row = (w + s * 8) * 16 + l15;
#pragma unroll
        for (int kc = 0; kc < 4; ++kc)
            aW[s][kc] = *(const bf16x8*)(WT + (size_t)row * 128 + kc * 32 + q * 8);
        bias4[s] = *(const float4*)(biasS + (w + s * 8) * 16 + q * 4);
    }

    // (3) scattered wx prefetch for d9/d8
    float wxA[4][2][4], wxB[2][2][4];
#pragma unroll
    for (int ct = 0; ct < 4; ++ct)
#pragma unroll
        for (int j = 0; j < 2; ++j) {
            int pl = ct * 8 + q * 2 + j;
            wx_unpack(*(const ushort4*)(wx + (size_t)(v9 + pl) * 512 + colf * 4), wxA[ct][j]);
        }
#pragma unroll
    for (int ct = 0; ct < 2; ++ct)
#pragma unroll
        for (int j = 0; j < 2; ++j) {
            int pl = ct * 8 + q * 2 + j;
            wx_unpack(*(const ushort4*)(wx + (size_t)(v8 + pl) * 512 + colf * 4), wxB[ct][j]);
        }

    // (4) pack F -> LDS
    *(uint4*)&FLS[SWZ(srow, scx)]      = pack_bf8(a0, a1);
    *(uint4*)&FLS[SWZ(32 + srow, scx)] = pack_bf8(b0, b1);
    lds_barrier();

    // ---- Phase 1: leaf GEMM + leaf epilogue ----
#pragma unroll
    for (int nt = 0; nt < 4; ++nt) {
        bf16x8 b[4];
#pragma unroll
        for (int kc = 0; kc < 4; ++kc)
            b[kc] = *(const bf16x8*)&FLS[SWZ(nt * 16 + l15, kc * 4 + q)];
        f32x4 acc[4] = {};
#pragma unroll
        for (int s = 0; s < 4; ++s)
#pragma unroll
            for (int kc = 0; kc < 4; ++kc)
                acc[s] = __builtin_amdgcn_mfma_f32_16x16x32_bf16(aW[s][kc], b[kc], acc[s], 0, 0, 0);

        int row = nt * 16 + l15;
        int colb = w * 16 + q * 4;
        float cv[4], hv[4];
#pragma unroll
        for (int r = 0; r < 4; ++r) {
            float pi = acc[0][r] + bias4[0][r];
            float po = acc[1][r] + bias4[1][r];
            float pu = acc[2][r] + bias4[2][r];
            float cn = sigmoidf_(pi) * tanhf_(pu);
            cv[r] = cn;
            hv[r] = sigmoidf_(po) * tanhf_(cn);
        }
        *(float4*)&h[(size_t)(vL + row) * 128 + colb] = *(float4*)hv;
        int chunk = colb >> 3, within = colb & 7;
        uint2 hp;
        hp.x = cvtpk(hv[0], hv[1]);
        hp.y = cvtpk(hv[2], hv[3]);
        *(uint2*)&HA[row * 128 + ((chunk ^ (row & 7)) * 8) + within] = hp;
        *(float4*)&CA[CAX(row, colb)] = *(float4*)cv;
    }
    bf16x8 bU[4][4];
    load_bU(UT, bU);    // after aW's last use
    lds_barrier();

    // ---- LEVEL A (d9): 32 parents from 64 leaf children ----
    float wxC[2][4], wxD[2][4], wxE[2][4];
    {
        f32x4 acc[4][4] = {};
        matvec_lds<4>(HA, bU, acc, l15, q);
        // prefetch deeper-level wx
#pragma unroll
        for (int j = 0; j < 2; ++j) {
            int pl = q * 2 + j;
            wx_unpack(*(const ushort4*)(wx + (size_t)(v7 + pl) * 512 + colf * 4), wxC[j]);
            wx_unpack(*(const ushort4*)(wx + (size_t)(v6 + pl) * 512 + colf * 4), wxD[j]);
            wx_unpack(*(const ushort4*)(wx + (size_t)(v5 + pl) * 512 + colf * 4), wxE[j]);
        }
        // HA fully consumed by all waves before H9 (aliasing HA) is written
        lds_barrier();
#pragma unroll
        for (int ct = 0; ct < 4; ++ct) {
            float cch[4];
#pragma unroll
            for (int r = 0; r < 4; ++r)
                cch[r] = CA[CAX(ct * 16 + q * 4 + r, colf)];
            float hv[2], cn[2];
            gate_epi(acc[ct], wxA[ct], cch, hv, cn);
#pragma unroll
            for (int j = 0; j < 2; ++j) {
                int pl = ct * 8 + q * 2 + j;
                h[(size_t)(v9 + pl) * 128 + colf] = hv[j];
                hwr(H9, pl, colf, hv[j]);
                C9v[CIDX(pl, colf)] = cn[j];
            }
        }
    }
    lds_barrier();

    // ---- LEVEL B (d8): 16 parents ----
    {
        float cch[2][4];
#pragma unroll
        for (int ct = 0; ct < 2; ++ct)
#pragma unroll
            for (int r = 0; r < 4; ++r)
                cch[ct][r] = C9v[CIDX(ct * 16 + q * 4 + r, colf)];
        f32x4 acc[2][4] = {};
        matvec_lds<2>(H9, bU, acc, l15, q);
#pragma unroll
        for (int ct = 0; ct < 2; ++ct) {
            float hv[2], cn[2];
            gate_epi(acc[ct], wxB[ct], cch[ct], hv, cn);
#pragma unroll
            for (int j = 0; j < 2; ++j) {
                int pl = ct * 8 + q * 2 + j;
                h[(size_t)(v8 + pl) * 128 + colf] = hv[j];
                hwr(H8, pl, colf, hv[j]);
                C8[CIDX(pl, colf)] = cn[j];
            }
        }
    }
    lds_barrier();

    // ---- LEVEL C (d7): 8 parents ----
    {
        float cch[4];
#pragma unroll
        for (int r = 0; r < 4; ++r)
            cch[r] = C8[CIDX(q * 4 + r, colf)];
        f32x4 acc[1][4] = {};
        matvec_lds<1>(H8, bU, acc, l15, q);
        float hv[2], cn[2];
        gate_epi(acc[0], wxC, cch, hv, cn);
#pragma unroll
        for (int j = 0; j < 2; ++j) {
            int pl = q * 2 + j;
            h[(size_t)(v7 + pl) * 128 + colf] = hv[j];
            hwr(H7, pl, colf, hv[j]);
            C7[CIDX(pl, colf)] = cn[j];
        }
    }
    lds_barrier();

    // ---- LEVEL D (d6): 4 parents ----
    {
        float cch[4];
#pragma unroll
        for (int r = 0; r < 4; ++r)
            cch[r] = C7[CIDX(q * 4 + r, colf)];
        f32x4 acc[1][4] = {};
        matvec_lds<1>(H7, bU, acc, l15, q);
        float hv[2], cn[2];
        gate_epi(acc[0], wxD, cch, hv, cn);
#pragma unroll
        for (int j = 0; j < 2; ++j) {
            int pl = q * 2 + j;
            if (pl < 4) {
                h[(size_t)(v6 + pl) * 128 + colf] = hv[j];
                hwr(H6, pl, colf, hv[j]);
                C6[CIDX(pl, colf)] = cn[j];
            }
        }
    }
    lds_barrier();

    // ---- LEVEL E (d5): 2 parents -> global h + c ----
    {
        float cch[4];
#pragma unroll
        for (int r = 0; r < 4; ++r)
            cch[r] = C6[CIDX(q * 4 + r, colf)];
        f32x4 acc[1][4] = {};
        matvec_lds<1>(H6, bU, acc, l15, q);
        float hv[2], cn[2];
        gate_epi(acc[0], wxE, cch, hv, cn);
#pragma unroll
        for (int j = 0; j < 2; ++j) {
            int pl = q * 2 + j;
            if (pl < 2) {
                h[(size_t)(v5 + pl) * 128 + colf] = hv[j];
                c[(size_t)(v5 + pl) * 128 + colf] = cn[j];
            }
        }
    }
}

// ---------------------------------------------------------------------------
// Tail: dep 4..0 (5 small groups), one block per tree. Unchanged.
__global__ __launch_bounds__(512, 1) void tail_k(const uint16_t* __restrict__ wx,
                                                 const uint16_t* __restrict__ UT,
                                                 const float* __restrict__ cglob,
                                                 float* __restrict__ h) {
    __shared__ uint16_t Hbuf[48 * 128];   // 12 KB
    __shared__ float CS[32 * 132];        // 16.9 KB
    bf16x8 bU[4][4];
    load_bU(UT, bU);
    const int tree = blockIdx.x;
    const int tid = threadIdx.x;
    const int w = tid >> 6, lane = tid & 63, q = lane >> 4, l15 = lane & 15;
    const int colf = w * 16 + l15;
    const int vbase = tree * MTREE;

    const int srow = tid >> 4, scx = tid & 15;
    const float* ssrc = h + (size_t)(vbase + 31 + srow) * 128 + scx * 8;
    float4 s0 = *(const float4*)ssrc;
    float4 s1 = *(const float4*)(ssrc + 4);

    float wx0[2][2][4], wx1[2][4], wx2[2][4], wx3[2][4], wx4[2][4];
#pragma unroll
    for (int ct = 0; ct < 2; ++ct)
#pragma unroll
        for (int j = 0; j < 2; ++j) {
            int pl = ct * 8 + q * 2 + j;
            wx_unpack(*(const ushort4*)(wx + (size_t)(vbase + 15 + pl) * 512 + colf * 4), wx0[ct][j]);
        }
#pragma unroll
    for (int j = 0; j < 2; ++j) {
        int pl = q * 2 + j;
        wx_unpack(*(const ushort4*)(wx + (size_t)(vbase + 7 + pl) * 512 + colf * 4), wx1[j]);
        wx_unpack(*(const ushort4*)(wx + (size_t)(vbase + 3 + pl) * 512 + colf * 4), wx2[j]);
        wx_unpack(*(const ushort4*)(wx + (size_t)(vbase + 1 + pl) * 512 + colf * 4), wx3[j]);
        wx_unpack(*(const ushort4*)(wx + (size_t)(vbase + 0 + pl) * 512 + colf * 4), wx4[j]);
    }
    float cgl[2][4];
#pragma unroll
    for (int ct = 0; ct < 2; ++ct)
#pragma unroll
        for (int r = 0; r < 4; ++r) {
            int cl = ct * 16 + q * 4 + r;
            cgl[ct][r] = cglob[(size_t)(vbase + 31 + cl) * 128 + colf];
        }

    *(uint4*)&Hbuf[SWZ(srow, scx)] = pack_bf8(s0, s1);
    lds_barrier();

    // ---- G0: dep4, 16 parents
    {
        f32x4 acc[2][4] = {};
        matvec_lds<2>(Hbuf, bU, acc, l15, q);
#pragma unroll
        for (int ct = 0; ct < 2; ++ct) {
            float hv[2], cn[2];
            gate_epi(acc[ct], wx0[ct], cgl[ct], hv, cn);
#pragma unroll
            for (int j = 0; j < 2; ++j) {
                int pl = ct * 8 + q * 2 + j;
                h[(size_t)(vbase + 15 + pl) * 128 + colf] = hv[j];
                hwr(Hbuf, 32 + pl, colf, hv[j]);
                CS[pl * 132 + colf] = cn[j];
            }
        }
    }
    lds_barrier();

    // ---- G1: dep3, 8 parents
    {
        float cch[4];
#pragma unroll
        for (int r = 0; r < 4; ++r)
            cch[r] = CS[(q * 4 + r) * 132 + colf];
        f32x4 acc[1][4] = {};
        matvec_lds<1>(&Hbuf[32 * 128], bU, acc, l15, q);
        float hv[2], cn[2];
        gate_epi(acc[0], wx1, cch, hv, cn);
#pragma unroll
        for (int j = 0; j < 2; ++j) {
            int pl = q * 2 + j;
            h[(size_t)(vbase + 7 + pl) * 128 + colf] = hv[j];
            hwr(Hbuf, pl, colf, hv[j]);
            CS[(16 + pl) * 132 + colf] = cn[j];
        }
    }
    lds_barrier();

    // ---- G2: dep2, 4 parents
    {
        float cch[4];
#pragma unroll
        for (int r = 0; r < 4; ++r)
            cch[r] = CS[(16 + q * 4 + r) * 132 + colf];
        f32x4 acc[1][4] = {};
        matvec_lds<1>(Hbuf, bU, acc, l15, q);
        float hv[2], cn[2];
        gate_epi(acc[0], wx2, cch, hv, cn);
#pragma unroll
        for (int j = 0; j < 2; ++j) {
            int pl = q * 2 + j;
            if (pl < 4) {
                h[(size_t)(vbase + 3 + pl) * 128 + colf] = hv[j];
                hwr(Hbuf, 32 + pl, colf, hv[j]);
                CS[pl * 132 + colf] = cn[j];
            }
        }
    }
    lds_barrier();

    // ---- G3: dep1, 2 parents
    {
        float cch[4];
#pragma unroll
        for (int r = 0; r < 4; ++r)
            cch[r] = CS[(q * 4 + r) * 132 + colf];
        f32x4 acc[1][4] = {};
        matvec_lds<1>(&Hbuf[32 * 128], bU, acc, l15, q);
        float hv[2], cn[2];
        gate_epi(acc[0], wx3, cch, hv, cn);
#pragma unroll
        for (int j = 0; j < 2; ++j) {
            int pl = q * 2 + j;
            if (pl < 2) {
                h[(size_t)(vbase + 1 + pl) * 128 + colf] = hv[j];
                hwr(Hbuf, pl, colf, hv[j]);
                CS[(16 + pl) * 132 + colf] = cn[j];
            }
        }
    }
    lds_barrier();

    // ---- G4: dep0, root
    {
        float cch[4];
#pragma unroll
        for (int r = 0; r < 4; ++r)
            cch[r] = CS[(16 + q * 4 + r) * 132 + colf];
        f32x4 acc[1][4] = {};
        matvec_lds<1>(Hbuf, bU, acc, l15, q);
        float hv[2], cn[2];
        gate_epi(acc[0], wx4, cch, hv, cn);
        if (q == 0) {
            h[(size_t)vbase * 128 + colf] = hv[0];
        }
    }
}

// ---------------------------------------------------------------------------
extern "C" void kernel_launch(void* const* d_in, const int* in_sizes, int n_in,
                              void* d_out, int out_size, void* d_ws, size_t ws_size,
                              hipStream_t stream) {
    const float* features = (const float*)d_in[0];
    const float* W_iou    = (const float*)d_in[1];
    const float* b_iou    = (const float*)d_in[2];
    const float* U_iou    = (const float*)d_in[3];
    const float* W_f      = (const float*)d_in[4];
    const float* b_f      = (const float*)d_in[5];
    const float* U_f      = (const float*)d_in[6];
    float* h = (float*)d_out;

    char* wp = (char*)d_ws;
    uint16_t* wx    = (uint16_t*)wp; wp += (size_t)NNODES * 512 * 2;
    float*    c     = (float*)wp;    wp += (size_t)NNODES * 128 * 4;
    uint16_t* WT    = (uint16_t*)wp; wp += 512 * 128 * 2;
    uint16_t* UT    = (uint16_t*)wp; wp += 512 * 128 * 2;
    float*    biasS = (float*)wp;    wp += 512 * 4;

    hipLaunchKernelGGL(prep_k, dim3(1025), dim3(128), 0, stream,
                       W_iou, W_f, U_iou, U_f, b_iou, b_f, WT, UT, biasS);
    hipLaunchKernelGGL(gemm_int_k, dim3(512), dim3(512), 0, stream,
                       features, WT, biasS, wx);
    hipLaunchKernelGGL(fused5L_k, dim3(512), dim3(512), 0, stream,
                       features, WT, biasS, wx, UT, h, c);
    hipLaunchKernelGGL(tail_k, dim3(32), dim3(512), 0, stream, wx, UT, c, h);
}

// Round 10
// 159.231 us; speedup vs baseline: 1.5148x; 1.0585x over previous
//
#include <hip/hip_runtime.h>
#include <math.h>
#include <stdint.h>

// TreeLSTM, 32 complete binary trees depth 10, heap order, d=128.
// R15: R14 falsified occupancy theory (2 blocks/CU capacity, same 53us).
//      Remaining waste: the wx producer/consumer split (gemm_int 22us +
//      67MB round trip + 62 scattered loads/thread in the climb).
//      fused6_k self-computes wx for its 63 internal nodes (d9..d4) via
//      in-block GEMM + 32KB LDS bounce (2 rounds, XOR unit^node swizzle),
//      climbs d4 too. tail_k self-computes wx for its 15 nodes (d3..d0).
//      gemm_int DELETED; no global wx array at all.

#define NTREES 32
#define MTREE 2047
#define NNODES (NTREES * MTREE)   // 65504

typedef __attribute__((ext_vector_type(8))) short bf16x8;
typedef __attribute__((ext_vector_type(4))) float f32x4;

__device__ __forceinline__ float sigmoidf_(float x) {
    return 1.0f / (1.0f + __expf(-x));
}
__device__ __forceinline__ float tanhf_(float x) {
    x = fminf(fmaxf(x, -10.0f), 10.0f);
    float e = __expf(2.0f * x);
    return (e - 1.0f) / (e + 1.0f);
}
__device__ __forceinline__ float bf2f(uint16_t b) {
    union { uint32_t u; float f; } v; v.u = ((uint32_t)b) << 16; return v.f;
}
__device__ __forceinline__ uint32_t cvtpk(float lo, float hi) {
    uint32_t r;
    asm("v_cvt_pk_bf16_f32 %0, %1, %2" : "=v"(r) : "v"(lo), "v"(hi));
    return r;
}
__device__ __forceinline__ uint16_t f2bf1(float f) {
    return (uint16_t)cvtpk(f, f);
}
__device__ __forceinline__ uint4 pack_bf8(float4 a, float4 b) {
    uint4 r;
    r.x = cvtpk(a.x, a.y); r.y = cvtpk(a.z, a.w);
    r.z = cvtpk(b.x, b.y); r.w = cvtpk(b.z, b.w);
    return r;
}

// raw workgroup barrier: LDS visibility only; global ops stay in flight
__device__ __forceinline__ void lds_barrier() {
    asm volatile("s_waitcnt lgkmcnt(0)" ::: "memory");
    __builtin_amdgcn_s_barrier();
    __builtin_amdgcn_sched_barrier(0);
}

// Swizzled LDS: bf16 rows of 128 (16 chunks of 16B), XOR by row&7.
#define SWZ(row, chunk) ((row) * 128 + (((chunk) ^ ((row) & 7)) * 8))
// f32 scalar c-buffer: float-level XOR
#define CIDX(row, col) ((row) * 128 + ((col) ^ (((row) & 7) << 2)))
// f32 float4-write buffer: 16B-chunk XOR
#define CAX(row, col) ((row) * 128 + (((((col) >> 2) ^ (((row) & 7) << 2)) & 31) << 2) + ((col) & 3))

__device__ __forceinline__ void hwr(uint16_t* buf, int row, int colf, float v) {
    buf[row * 128 + (((colf >> 3) ^ (row & 7)) * 8) + (colf & 7)] = f2bf1(v);
}

__device__ __forceinline__ void wx_unpack(ushort4 g, float o[4]) {
    o[0] = bf2f(g.x); o[1] = bf2f(g.y); o[2] = bf2f(g.z); o[3] = bf2f(g.w);
}

__device__ __forceinline__ void gate_epi(const f32x4 acc[4], const float wxj[2][4],
                                         const float cch[4], float hv[2], float cn[2]) {
    float fc[4];
#pragma unroll
    for (int r = 0; r < 4; ++r)
        fc[r] = sigmoidf_(acc[3][r] + wxj[r >> 1][3]) * cch[r];
#pragma unroll
    for (int j = 0; j < 2; ++j) {
        float ip = acc[0][2 * j] + acc[0][2 * j + 1] + wxj[j][0];
        float op = acc[1][2 * j] + acc[1][2 * j + 1] + wxj[j][1];
        float up = acc[2][2 * j] + acc[2][2 * j + 1] + wxj[j][2];
        cn[j] = sigmoidf_(ip) * tanhf_(up) + fc[2 * j] + fc[2 * j + 1];
        hv[j] = sigmoidf_(op) * tanhf_(cn[j]);
    }
}

// ---------------------------------------------------------------------------
__global__ __launch_bounds__(128) void prep_k(const float* __restrict__ Wiou,
                                              const float* __restrict__ Wf,
                                              const float* __restrict__ Uiou,
                                              const float* __restrict__ Uf,
                                              const float* __restrict__ biou,
                                              const float* __restrict__ bf,
                                              uint16_t* __restrict__ WT,
                                              uint16_t* __restrict__ UT,
                                              float* __restrict__ biasS) {
    int n = blockIdx.x, k = threadIdx.x;
    if (n < 512) {
        WT[n * 128 + k] = f2bf1(n < 384 ? Wiou[k * 384 + n] : Wf[k * 128 + (n - 384)]);
    } else if (n < 1024) {
        int m = n - 512;
        UT[m * 128 + k] = f2bf1(m < 384 ? Uiou[k * 384 + m] : Uf[k * 128 + (m - 384)]);
    } else {
#pragma unroll
        for (int r = 0; r < 4; ++r) {
            int j = r * 128 + k;
            biasS[j] = j < 384 ? biou[j] : bf[j - 384];
        }
    }
}

// ---------------------------------------------------------------------------
__device__ __forceinline__ void load_bU(const uint16_t* __restrict__ UT, bf16x8 bU[4][4]) {
    const int tid = threadIdx.x;
    const int w = tid >> 6, lane = tid & 63, q = lane >> 4, l15 = lane & 15;
#pragma unroll
    for (int s = 0; s < 4; ++s) {
        int row = (w + s * 8) * 16 + l15;
#pragma unroll
        for (int kc = 0; kc < 4; ++kc)
            bU[s][kc] = *(const bf16x8*)(UT + (size_t)row * 128 + kc * 32 + q * 8);
    }
}

template<int NCT>
__device__ __forceinline__ void matvec_lds(const uint16_t* __restrict__ H,
                                           const bf16x8 bU[4][4],
                                           f32x4 acc[NCT][4], int l15, int q) {
#pragma unroll
    for (int ct = 0; ct < NCT; ++ct) {
        bf16x8 a[4];
#pragma unroll
        for (int kc = 0; kc < 4; ++kc)
            a[kc] = *(const bf16x8*)&H[SWZ(ct * 16 + l15, kc * 4 + q)];
#pragma unroll
        for (int s = 0; s < 4; ++s)
#pragma unroll
            for (int kc = 0; kc < 4; ++kc)
                acc[ct][s] = __builtin_amdgcn_mfma_f32_16x16x32_bf16(a[kc], bU[s][kc], acc[ct][s], 0, 0, 0);
    }
}

// ---------------------------------------------------------------------------
// Fused: internal-wx GEMM (d9..d4, LDS bounce) + leaf GEMM + climb d9..d4.
// LDS pool 64KB. Phase W: FINT [0,16K), BNC [16K,48K).
// Phase 1+: FLS->C9v [0,16K); HA->H9,H8,H7(->H5) [16K,32K);
//           CA->C8,C7(->C5),C6,H6 [32K,64K).
__global__ __launch_bounds__(512, 2) void fused6_k(const float* __restrict__ F,
                                                   const uint16_t* __restrict__ WT,
                                                   const float* __restrict__ biasS,
                                                   const uint16_t* __restrict__ UT,
                                                   float* __restrict__ h,
                                                   float* __restrict__ c) {
    __shared__ __align__(16) char SM[65536];
    uint16_t* FINT = (uint16_t*)SM;              // 16KB, 64 rows
    uint16_t* BNC  = (uint16_t*)(SM + 16384);    // 32KB, 32 slots x 1KB
    uint16_t* FLS = (uint16_t*)SM;
    float*    C9v = (float*)SM;
    uint16_t* HA  = (uint16_t*)(SM + 16384);
    uint16_t* H9  = (uint16_t*)(SM + 16384);
    uint16_t* H8  = (uint16_t*)(SM + 24576);
    uint16_t* H7  = (uint16_t*)(SM + 28672);
    uint16_t* H5  = (uint16_t*)(SM + 28672);     // reuse H7 after level D
    float*    CA  = (float*)(SM + 32768);
    float*    C8  = (float*)(SM + 32768);
    float*    C7  = (float*)(SM + 40960);
    float*    C5  = (float*)(SM + 40960);        // reuse C7 after level D
    float*    C6  = (float*)(SM + 49152);
    uint16_t* H6  = (uint16_t*)(SM + 57344);

    const int tid = threadIdx.x;
    const int w = tid >> 6, lane = tid & 63, q = lane >> 4, l15 = lane & 15;
    const int colf = w * 16 + l15;
    const int colb = w * 16 + q * 4;
    const int tree = blockIdx.x >> 4;
    const int pos4 = blockIdx.x & 15;
    const int vbase = tree * MTREE;
    const int v4 = vbase + 15 + pos4;
    const int v5 = vbase + 31 + 2 * pos4;
    const int v6 = vbase + 63 + 4 * pos4;
    const int v7 = vbase + 127 + 8 * pos4;
    const int v8 = vbase + 255 + 16 * pos4;
    const int v9 = vbase + 511 + 32 * pos4;
    const int vL = vbase + 1023 + 64 * pos4;

    // FINT row -> global node (rows 0..63)
    auto fint_node = [&](int row) -> int {
        if (row < 32) return v9 + row;
        if (row < 48) return v8 + row - 32;
        if (row < 56) return v7 + row - 48;
        if (row < 60) return v6 + row - 56;
        if (row < 62) return v5 + row - 60;
        return v4;                       // rows 62,63 (63 = dummy dup)
    };

    // (1) issue FINT global loads (oldest in queue)
    const int srow = tid >> 4, scx = tid & 15;
    float4 i0[2], i1[2];
#pragma unroll
    for (int t = 0; t < 2; ++t) {
        int ci = t * 512 + tid;
        int row = ci >> 4, cx = ci & 15;
        const float* src = F + (size_t)fint_node(row) * 128 + cx * 8;
        i0[t] = *(const float4*)src;
        i1[t] = *(const float4*)(src + 4);
    }
    // (2) issue leaf F loads (stay in flight through phase W)
    const float* sa = F + (size_t)(vL + srow) * 128 + scx * 8;
    const float* sb = F + (size_t)(vL + 32 + srow) * 128 + scx * 8;
    float4 a0 = *(const float4*)sa, a1 = *(const float4*)(sa + 4);
    float4 b0 = *(const float4*)sb, b1 = *(const float4*)(sb + 4);

    // (3) W weights + bias (L2-warm)
    bf16x8 aW[4][4];
    float4 bias4[4];
#pragma unroll
    for (int s = 0; s < 4; ++s) {
        int row = (w + s * 8) * 16 + l15;
#pragma unroll
        for (int kc = 0; kc < 4; ++kc)
            aW[s][kc] = *(const bf16x8*)(WT + (size_t)row * 128 + kc * 32 + q * 8);
        bias4[s] = *(const float4*)(biasS + (w + s * 8) * 16 + q * 4);
    }

    // (4) pack FINT -> LDS
#pragma unroll
    for (int t = 0; t < 2; ++t) {
        int ci = t * 512 + tid;
        int row = ci >> 4, cx = ci & 15;
        *(uint4*)&FINT[SWZ(row, cx)] = pack_bf8(i0[t], i1[t]);
    }
    lds_barrier();

    // GEMM one 16-node tile of FINT -> bounce slot (gate-interleaved bf16,
    // unit index XOR node&15; bias included).
    auto wx_tile = [&](int baseRow, int slotBase) {
        bf16x8 b[4];
#pragma unroll
        for (int kc = 0; kc < 4; ++kc)
            b[kc] = *(const bf16x8*)&FINT[SWZ(baseRow + l15, kc * 4 + q)];
        f32x4 acc[4] = {};
#pragma unroll
        for (int s = 0; s < 4; ++s)
#pragma unroll
            for (int kc = 0; kc < 4; ++kc)
                acc[s] = __builtin_amdgcn_mfma_f32_16x16x32_bf16(aW[s][kc], b[kc], acc[s], 0, 0, 0);
        int n = slotBase + l15;
#pragma unroll
        for (int r = 0; r < 4; ++r) {
            uint2 g;
            g.x = cvtpk(acc[0][r] + bias4[0][r], acc[1][r] + bias4[1][r]);
            g.y = cvtpk(acc[2][r] + bias4[2][r], acc[3][r] + bias4[3][r]);
            int f = colb + r;
            *(uint2*)&BNC[n * 512 + ((f ^ (n & 15)) << 2)] = g;
        }
    };
    auto bnc_rd = [&](int n, float o[4]) {
        wx_unpack(*(const ushort4*)&BNC[n * 512 + ((colf ^ (n & 15)) << 2)], o);
    };

    float wxA[4][2][4], wxB[2][2][4], wxC[2][4], wxD[2][4], wxE[2][4], wxFp[2][4];

    // ---- Round A: d9 (32 nodes) ----
    wx_tile(0, 0);
    wx_tile(16, 16);
    lds_barrier();
#pragma unroll
    for (int ct = 0; ct < 4; ++ct)
#pragma unroll
        for (int j = 0; j < 2; ++j)
            bnc_rd(ct * 8 + q * 2 + j, wxA[ct][j]);
    lds_barrier();

    // ---- Round B: d8 (16) + packed d7/d6/d5/d4 (15) ----
    wx_tile(32, 0);
    wx_tile(48, 16);
    lds_barrier();
#pragma unroll
    for (int ct = 0; ct < 2; ++ct)
#pragma unroll
        for (int j = 0; j < 2; ++j)
            bnc_rd(ct * 8 + q * 2 + j, wxB[ct][j]);
#pragma unroll
    for (int j = 0; j < 2; ++j) {
        int pl = q * 2 + j;
        bnc_rd(16 + pl, wxC[j]);
        bnc_rd(24 + (pl & 3), wxD[j]);
        bnc_rd(28 + (pl & 1), wxE[j]);
        bnc_rd(30, wxFp[j]);
    }
    // pack leaf F -> FLS (overwrites FINT; FINT reads all completed above)
    *(uint4*)&FLS[SWZ(srow, scx)]      = pack_bf8(a0, a1);
    *(uint4*)&FLS[SWZ(32 + srow, scx)] = pack_bf8(b0, b1);
    lds_barrier();

    // ---- Phase 1: leaf GEMM + leaf epilogue ----
#pragma unroll
    for (int nt = 0; nt < 4; ++nt) {
        bf16x8 b[4];
#pragma unroll
        for (int kc = 0; kc < 4; ++kc)
            b[kc] = *(const bf16x8*)&FLS[SWZ(nt * 16 + l15, kc * 4 + q)];
        f32x4 acc[4] = {};
#pragma unroll
        for (int s = 0; s < 4; ++s)
#pragma unroll
            for (int kc = 0; kc < 4; ++kc)
                acc[s] = __builtin_amdgcn_mfma_f32_16x16x32_bf16(aW[s][kc], b[kc], acc[s], 0, 0, 0);

        int row = nt * 16 + l15;
        float cv[4], hv[4];
#pragma unroll
        for (int r = 0; r < 4; ++r) {
            float pi = acc[0][r] + bias4[0][r];
            float po = acc[1][r] + bias4[1][r];
            float pu = acc[2][r] + bias4[2][r];
            float cn = sigmoidf_(pi) * tanhf_(pu);
            cv[r] = cn;
            hv[r] = sigmoidf_(po) * tanhf_(cn);
        }
        *(float4*)&h[(size_t)(vL + row) * 128 + colb] = *(float4*)hv;
        int chunk = colb >> 3, within = colb & 7;
        uint2 hp;
        hp.x = cvtpk(hv[0], hv[1]);
        hp.y = cvtpk(hv[2], hv[3]);
        *(uint2*)&HA[row * 128 + ((chunk ^ (row & 7)) * 8) + within] = hp;
        *(float4*)&CA[CAX(row, colb)] = *(float4*)cv;
    }
    bf16x8 bU[4][4];
    load_bU(UT, bU);    // after aW's last use
    lds_barrier();

    // ---- LEVEL A (d9): 32 parents from 64 leaf children ----
    {
        f32x4 acc[4][4] = {};
        matvec_lds<4>(HA, bU, acc, l15, q);
        // HA fully consumed before H9 (aliasing HA) is written
        lds_barrier();
#pragma unroll
        for (int ct = 0; ct < 4; ++ct) {
            float cch[4];
#pragma unroll
            for (int r = 0; r < 4; ++r)
                cch[r] = CA[CAX(ct * 16 + q * 4 + r, colf)];
            float hv[2], cn[2];
            gate_epi(acc[ct], wxA[ct], cch, hv, cn);
#pragma unroll
            for (int j = 0; j < 2; ++j) {
                int pl = ct * 8 + q * 2 + j;
                h[(size_t)(v9 + pl) * 128 + colf] = hv[j];
                hwr(H9, pl, colf, hv[j]);
                C9v[CIDX(pl, colf)] = cn[j];
            }
        }
    }
    lds_barrier();

    // ---- LEVEL B (d8): 16 parents ----
    {
        float cch[2][4];
#pragma unroll
        for (int ct = 0; ct < 2; ++ct)
#pragma unroll
            for (int r = 0; r < 4; ++r)
                cch[ct][r] = C9v[CIDX(ct * 16 + q * 4 + r, colf)];
        f32x4 acc[2][4] = {};
        matvec_lds<2>(H9, bU, acc, l15, q);
#pragma unroll
        for (int ct = 0; ct < 2; ++ct) {
            float hv[2], cn[2];
            gate_epi(acc[ct], wxB[ct], cch[ct], hv, cn);
#pragma unroll
            for (int j = 0; j < 2; ++j) {
                int pl = ct * 8 + q * 2 + j;
                h[(size_t)(v8 + pl) * 128 + colf] = hv[j];
                hwr(H8, pl, colf, hv[j]);
                C8[CIDX(pl, colf)] = cn[j];
            }
        }
    }
    lds_barrier();

    // ---- LEVEL C (d7): 8 parents ----
    {
        float cch[4];
#pragma unroll
        for (int r = 0; r < 4; ++r)
            cch[r] = C8[CIDX(q * 4 + r, colf)];
        f32x4 acc[1][4] = {};
        matvec_lds<1>(H8, bU, acc, l15, q);
        float hv[2], cn[2];
        gate_epi(acc[0], wxC, cch, hv, cn);
#pragma unroll
        for (int j = 0; j < 2; ++j) {
            int pl = q * 2 + j;
            h[(size_t)(v7 + pl) * 128 + colf] = hv[j];
            hwr(H7, pl, colf, hv[j]);
            C7[CIDX(pl, colf)] = cn[j];
        }
    }
    lds_barrier();

    // ---- LEVEL D (d6): 4 parents ----
    {
        float cch[4];
#pragma unroll
        for (int r = 0; r < 4; ++r)
            cch[r] = C7[CIDX(q * 4 + r, colf)];
        f32x4 acc[1][4] = {};
        matvec_lds<1>(H7, bU, acc, l15, q);
        float hv[2], cn[2];
        gate_epi(acc[0], wxD, cch, hv, cn);
#pragma unroll
        for (int j = 0; j < 2; ++j) {
            int pl = q * 2 + j;
            if (pl < 4) {
                h[(size_t)(v6 + pl) * 128 + colf] = hv[j];
                hwr(H6, pl, colf, hv[j]);
                C6[CIDX(pl, colf)] = cn[j];
            }
        }
    }
    lds_barrier();

    // ---- LEVEL E (d5): 2 parents -> global h + LDS H5/C5 (reuse H7/C7) ----
    {
        float cch[4];
#pragma unroll
        for (int r = 0; r < 4; ++r)
            cch[r] = C6[CIDX(q * 4 + r, colf)];
        f32x4 acc[1][4] = {};
        matvec_lds<1>(H6, bU, acc, l15, q);
        float hv[2], cn[2];
        gate_epi(acc[0], wxE, cch, hv, cn);
#pragma unroll
        for (int j = 0; j < 2; ++j) {
            int pl = q * 2 + j;
            if (pl < 2) {
                h[(size_t)(v5 + pl) * 128 + colf] = hv[j];
                hwr(H5, pl, colf, hv[j]);
                C5[CIDX(pl, colf)] = cn[j];
            }
        }
    }
    lds_barrier();

    // ---- LEVEL F (d4): 1 parent -> global h + c (tail handoff) ----
    {
        float cch[4];
#pragma unroll
        for (int r = 0; r < 4; ++r)
            cch[r] = C5[CIDX(q * 4 + r, colf)];
        f32x4 acc[1][4] = {};
        matvec_lds<1>(H5, bU, acc, l15, q);
        float hv[2], cn[2];
        gate_epi(acc[0], wxFp, cch, hv, cn);
        if (q == 0) {
            // pl = q*2+j valid only for j==0 (pl==0)
            h[(size_t)v4 * 128 + colf] = hv[0];
            c[(size_t)v4 * 128 + colf] = cn[0];
        }
    }
}

// ---------------------------------------------------------------------------
// Tail: self-computed wx for d3..d0 (15 nodes), then climb. 1 block/tree.
// Pool 29.2KB: Hbuf 48 rows [0,12288); CS [12288,29184).
// Phase W: FINTt [0,4096); BNCt [4096,20480) (aliases, barrier-separated).
__global__ __launch_bounds__(512, 1) void tail_k(const float* __restrict__ F,
                                                 const uint16_t* __restrict__ WT,
                                                 const float* __restrict__ biasS,
                                                 const uint16_t* __restrict__ UT,
                                                 const float* __restrict__ cglob,
                                                 float* __restrict__ h) {
    __shared__ __align__(16) char SMt[29184];
    uint16_t* Hbuf  = (uint16_t*)SMt;
    float*    CS    = (float*)(SMt + 12288);
    uint16_t* FINTt = (uint16_t*)SMt;
    uint16_t* BNCt  = (uint16_t*)(SMt + 4096);

    const int tid = threadIdx.x;
    const int w = tid >> 6, lane = tid & 63, q = lane >> 4, l15 = lane & 15;
    const int colf = w * 16 + l15;
    const int colb = w * 16 + q * 4;
    const int tree = blockIdx.x;
    const int vb = tree * MTREE;

    // FINTt row -> node: 0-7 d3(j=7..14), 8-11 d2(j=3..6), 12-13 d1, 14 d0
    auto tnode = [&](int row) -> int {
        if (row < 8) return vb + 7 + row;
        if (row < 12) return vb + 3 + (row - 8);
        if (row < 14) return vb + 1 + (row - 12);
        return vb;
    };

    // (1) issue global loads: internal F rows, d4 h rows, d4 c
    float4 fi0, fi1, hh0, hh1;
    if (tid < 256) {
        int row = tid >> 4, cx = tid & 15;
        const float* fsrc = F + (size_t)tnode(row) * 128 + cx * 8;
        fi0 = *(const float4*)fsrc;
        fi1 = *(const float4*)(fsrc + 4);
        const float* hsrc = h + (size_t)(vb + 15 + row) * 128 + cx * 8;
        hh0 = *(const float4*)hsrc;
        hh1 = *(const float4*)(hsrc + 4);
    }
    float cgl[4];
#pragma unroll
    for (int r = 0; r < 4; ++r) {
        int cl = q * 4 + r;
        cgl[r] = cglob[(size_t)(vb + 15 + cl) * 128 + colf];
    }

    // (2) weights (L2-warm)
    bf16x8 aW[4][4];
    float4 bias4[4];
#pragma unroll
    for (int s = 0; s < 4; ++s) {
        int row = (w + s * 8) * 16 + l15;
#pragma unroll
        for (int kc = 0; kc < 4; ++kc)
            aW[s][kc] = *(const bf16x8*)(WT + (size_t)row * 128 + kc * 32 + q * 8);
        bias4[s] = *(const float4*)(biasS + (w + s * 8) * 16 + q * 4);
    }
    bf16x8 bU[4][4];
    load_bU(UT, bU);

    // (3) pack FINTt
    if (tid < 256) {
        int row = tid >> 4, cx = tid & 15;
        *(uint4*)&FINTt[SWZ(row, cx)] = pack_bf8(fi0, fi1);
    }
    lds_barrier();

    // ---- phase W: one GEMM tile -> bounce ----
    {
        bf16x8 b[4];
#pragma unroll
        for (int kc = 0; kc < 4; ++kc)
            b[kc] = *(const bf16x8*)&FINTt[SWZ(l15, kc * 4 + q)];
        f32x4 acc[4] = {};
#pragma unroll
        for (int s = 0; s < 4; ++s)
#pragma unroll
            for (int kc = 0; kc < 4; ++kc)
                acc[s] = __builtin_amdgcn_mfma_f32_16x16x32_bf16(aW[s][kc], b[kc], acc[s], 0, 0, 0);
        int n = l15;
#pragma unroll
        for (int r = 0; r < 4; ++r) {
            uint2 g;
            g.x = cvtpk(acc[0][r] + bias4[0][r], acc[1][r] + bias4[1][r]);
            g.y = cvtpk(acc[2][r] + bias4[2][r], acc[3][r] + bias4[3][r]);
            int f = colb + r;
            *(uint2*)&BNCt[n * 512 + ((f ^ (n & 15)) << 2)] = g;
        }
    }
    lds_barrier();

    float wx1[2][4], wx2[2][4], wx3[2][4], wx4p[2][4];
#pragma unroll
    for (int j = 0; j < 2; ++j) {
        int pl = q * 2 + j;
        wx_unpack(*(const ushort4*)&BNCt[pl * 512 + ((colf ^ (pl & 15)) << 2)], wx1[j]);
        int n2 = 8 + (pl & 3);
        wx_unpack(*(const ushort4*)&BNCt[n2 * 512 + ((colf ^ (n2 & 15)) << 2)], wx2[j]);
        int n3 = 12 + (pl & 1);
        wx_unpack(*(const ushort4*)&BNCt[n3 * 512 + ((colf ^ (n3 & 15)) << 2)], wx3[j]);
        wx_unpack(*(const ushort4*)&BNCt[14 * 512 + ((colf ^ 14) << 2)], wx4p[j]);
    }
    lds_barrier();   // BNCt dead

    // (4) pack d4 h -> Hbuf rows 0..15
    if (tid < 256) {
        int row = tid >> 4, cx = tid & 15;
        *(uint4*)&Hbuf[SWZ(row, cx)] = pack_bf8(hh0, hh1);
    }
    lds_barrier();

    // ---- G1: d3, 8 parents (children d4 rows 0..15, c from global) ----
    {
        f32x4 acc[1][4] = {};
        matvec_lds<1>(Hbuf, bU, acc, l15, q);
        float hv[2], cn[2];
        gate_epi(acc[0], wx1, cgl, hv, cn);
#pragma unroll
        for (int j = 0; j < 2; ++j) {
            int pl = q * 2 + j;        // 0..7 all valid
            h[(size_t)(vb + 7 + pl) * 128 + colf] = hv[j];
            hwr(Hbuf, 16 + pl, colf, hv[j]);
            CS[pl * 132 + colf] = cn[j];
        }
    }
    lds_barrier();

    // ---- G2: d2, 4 parents (children d3 at base 16) ----
    {
        float cch[4];
#pragma unroll
        for (int r = 0; r < 4; ++r)
            cch[r] = CS[(q * 4 + r) * 132 + colf];
        f32x4 acc[1][4] = {};
        matvec_lds<1>(&Hbuf[16 * 128], bU, acc, l15, q);
        float hv[2], cn[2];
        gate_epi(acc[0], wx2, cch, hv, cn);
#pragma unroll
        for (int j = 0; j < 2; ++j) {
            int pl = q * 2 + j;
            if (pl < 4) {
                h[(size_t)(vb + 3 + pl) * 128 + colf] = hv[j];
                hwr(Hbuf, 32 + pl, colf, hv[j]);
                CS[(16 + pl) * 132 + colf] = cn[j];
            }
        }
    }
    lds_barrier();

    // ---- G3: d1, 2 parents (children d2 at base 32) ----
    {
        float cch[4];
#pragma unroll
        for (int r = 0; r < 4; ++r)
            cch[r] = CS[(16 + q * 4 + r) * 132 + colf];
        f32x4 acc[1][4] = {};
        matvec_lds<1>(&Hbuf[32 * 128], bU, acc, l15, q);
        float hv[2], cn[2];
        gate_epi(acc[0], wx3, cch, hv, cn);
#pragma unroll
        for (int j = 0; j < 2; ++j) {
            int pl = q * 2 + j;
            if (pl < 2) {
                h[(size_t)(vb + 1 + pl) * 128 + colf] = hv[j];
                hwr(Hbuf, 40 + pl, colf, hv[j]);
                CS[pl * 132 + colf] = cn[j];
            }
        }
    }
    lds_barrier();

    // ---- G4: d0, root (children d1 at base 40) ----
    {
        float cch[4];
#pragma unroll
        for (int r = 0; r < 4; ++r)
            cch[r] = CS[(q * 4 + r) * 132 + colf];
        f32x4 acc[1][4] = {};
        matvec_lds<1>(&Hbuf[40 * 128], bU, acc, l15, q);
        float hv[2], cn[2];
        gate_epi(acc[0], wx4p, cch, hv, cn);
        if (q == 0) {
            h[(size_t)vb * 128 + colf] = hv[0];
        }
    }
}

// ---------------------------------------------------------------------------
extern "C" void kernel_launch(void* const* d_in, const int* in_sizes, int n_in,
                              void* d_out, int out_size, void* d_ws, size_t ws_size,
                              hipStream_t stream) {
    const float* features = (const float*)d_in[0];
    const float* W_iou    = (const float*)d_in[1];
    const float* b_iou    = (const float*)d_in[2];
    const float* U_iou    = (const float*)d_in[3];
    const float* W_f      = (const float*)d_in[4];
    const float* b_f      = (const float*)d_in[5];
    const float* U_f      = (const float*)d_in[6];
    float* h = (float*)d_out;

    char* wp = (char*)d_ws;
    float*    c     = (float*)wp;    wp += (size_t)NNODES * 128 * 4;
    uint16_t* WT    = (uint16_t*)wp; wp += 512 * 128 * 2;
    uint16_t* UT    = (uint16_t*)wp; wp += 512 * 128 * 2;
    float*    biasS = (float*)wp;    wp += 512 * 4;

    hipLaunchKernelGGL(prep_k, dim3(1025), dim3(128), 0, stream,
                       W_iou, W_f, U_iou, U_f, b_iou, b_f, WT, UT, biasS);
    hipLaunchKernelGGL(fused6_k, dim3(512), dim3(512), 0, stream,
                       features, WT, biasS, UT, h, c);
    hipLaunchKernelGGL(tail_k, dim3(32), dim3(512), 0, stream,
                       features, WT, biasS, UT, c, h);
}

// Round 11
// 156.779 us; speedup vs baseline: 1.5385x; 1.0156x over previous
//
#include <hip/hip_runtime.h>
#include <math.h>
#include <stdint.h>

// TreeLSTM, 32 complete binary trees depth 10, heap order, d=128.
// R16: R15 decomposition: fused6 itself regressed 53+25 -> 101us (phase W
//      added 4 barrier-separated rounds to a chain-bound kernel; all pipes
//      DROPPED while dur doubled); net win was workspace-fill shrinkage
//      (fills are inside measured dur). Fixes:
//      (1) single barrier-free GEMM mega-phase: FINT+FLS staged in dedicated
//          LDS, BNC widened to 64 slots, all 128 MFMAs (4 wx tiles + leaf)
//          back-to-back; barriers 12 -> 8. 144KB LDS, 1 block/CU (R14
//          proved blocks/CU don't matter for this chain-bound kernel).
//      (2) c workspace compacted 33.5MB -> 0.26MB (d4 rows only, indexed
//          by blockIdx) -> total workspace <1MB, fills ~0.

#define NTREES 32
#define MTREE 2047
#define NNODES (NTREES * MTREE)   // 65504

typedef __attribute__((ext_vector_type(8))) short bf16x8;
typedef __attribute__((ext_vector_type(4))) float f32x4;

__device__ __forceinline__ float sigmoidf_(float x) {
    return 1.0f / (1.0f + __expf(-x));
}
__device__ __forceinline__ float tanhf_(float x) {
    x = fminf(fmaxf(x, -10.0f), 10.0f);
    float e = __expf(2.0f * x);
    return (e - 1.0f) / (e + 1.0f);
}
__device__ __forceinline__ float bf2f(uint16_t b) {
    union { uint32_t u; float f; } v; v.u = ((uint32_t)b) << 16; return v.f;
}
__device__ __forceinline__ uint32_t cvtpk(float lo, float hi) {
    uint32_t r;
    asm("v_cvt_pk_bf16_f32 %0, %1, %2" : "=v"(r) : "v"(lo), "v"(hi));
    return r;
}
__device__ __forceinline__ uint16_t f2bf1(float f) {
    return (uint16_t)cvtpk(f, f);
}
__device__ __forceinline__ uint4 pack_bf8(float4 a, float4 b) {
    uint4 r;
    r.x = cvtpk(a.x, a.y); r.y = cvtpk(a.z, a.w);
    r.z = cvtpk(b.x, b.y); r.w = cvtpk(b.z, b.w);
    return r;
}

// raw workgroup barrier: LDS visibility only; global ops stay in flight
__device__ __forceinline__ void lds_barrier() {
    asm volatile("s_waitcnt lgkmcnt(0)" ::: "memory");
    __builtin_amdgcn_s_barrier();
    __builtin_amdgcn_sched_barrier(0);
}

// Swizzled LDS: bf16 rows of 128 (16 chunks of 16B), XOR by row&7.
#define SWZ(row, chunk) ((row) * 128 + (((chunk) ^ ((row) & 7)) * 8))
// f32 scalar c-buffer: float-level XOR
#define CIDX(row, col) ((row) * 128 + ((col) ^ (((row) & 7) << 2)))
// f32 float4-write buffer: 16B-chunk XOR
#define CAX(row, col) ((row) * 128 + (((((col) >> 2) ^ (((row) & 7) << 2)) & 31) << 2) + ((col) & 3))

__device__ __forceinline__ void hwr(uint16_t* buf, int row, int colf, float v) {
    buf[row * 128 + (((colf >> 3) ^ (row & 7)) * 8) + (colf & 7)] = f2bf1(v);
}

__device__ __forceinline__ void wx_unpack(ushort4 g, float o[4]) {
    o[0] = bf2f(g.x); o[1] = bf2f(g.y); o[2] = bf2f(g.z); o[3] = bf2f(g.w);
}

__device__ __forceinline__ void gate_epi(const f32x4 acc[4], const float wxj[2][4],
                                         const float cch[4], float hv[2], float cn[2]) {
    float fc[4];
#pragma unroll
    for (int r = 0; r < 4; ++r)
        fc[r] = sigmoidf_(acc[3][r] + wxj[r >> 1][3]) * cch[r];
#pragma unroll
    for (int j = 0; j < 2; ++j) {
        float ip = acc[0][2 * j] + acc[0][2 * j + 1] + wxj[j][0];
        float op = acc[1][2 * j] + acc[1][2 * j + 1] + wxj[j][1];
        float up = acc[2][2 * j] + acc[2][2 * j + 1] + wxj[j][2];
        cn[j] = sigmoidf_(ip) * tanhf_(up) + fc[2 * j] + fc[2 * j + 1];
        hv[j] = sigmoidf_(op) * tanhf_(cn[j]);
    }
}

// ---------------------------------------------------------------------------
__global__ __launch_bounds__(128) void prep_k(const float* __restrict__ Wiou,
                                              const float* __restrict__ Wf,
                                              const float* __restrict__ Uiou,
                                              const float* __restrict__ Uf,
                                              const float* __restrict__ biou,
                                              const float* __restrict__ bf,
                                              uint16_t* __restrict__ WT,
                                              uint16_t* __restrict__ UT,
                                              float* __restrict__ biasS) {
    int n = blockIdx.x, k = threadIdx.x;
    if (n < 512) {
        WT[n * 128 + k] = f2bf1(n < 384 ? Wiou[k * 384 + n] : Wf[k * 128 + (n - 384)]);
    } else if (n < 1024) {
        int m = n - 512;
        UT[m * 128 + k] = f2bf1(m < 384 ? Uiou[k * 384 + m] : Uf[k * 128 + (m - 384)]);
    } else {
#pragma unroll
        for (int r = 0; r < 4; ++r) {
            int j = r * 128 + k;
            biasS[j] = j < 384 ? biou[j] : bf[j - 384];
        }
    }
}

// ---------------------------------------------------------------------------
__device__ __forceinline__ void load_bU(const uint16_t* __restrict__ UT, bf16x8 bU[4][4]) {
    const int tid = threadIdx.x;
    const int w = tid >> 6, lane = tid & 63, q = lane >> 4, l15 = lane & 15;
#pragma unroll
    for (int s = 0; s < 4; ++s) {
        int row = (w + s * 8) * 16 + l15;
#pragma unroll
        for (int kc = 0; kc < 4; ++kc)
            bU[s][kc] = *(const bf16x8*)(UT + (size_t)row * 128 + kc * 32 + q * 8);
    }
}

template<int NCT>
__device__ __forceinline__ void matvec_lds(const uint16_t* __restrict__ H,
                                           const bf16x8 bU[4][4],
                                           f32x4 acc[NCT][4], int l15, int q) {
#pragma unroll
    for (int ct = 0; ct < NCT; ++ct) {
        bf16x8 a[4];
#pragma unroll
        for (int kc = 0; kc < 4; ++kc)
            a[kc] = *(const bf16x8*)&H[SWZ(ct * 16 + l15, kc * 4 + q)];
#pragma unroll
        for (int s = 0; s < 4; ++s)
#pragma unroll
            for (int kc = 0; kc < 4; ++kc)
                acc[ct][s] = __builtin_amdgcn_mfma_f32_16x16x32_bf16(a[kc], bU[s][kc], acc[ct][s], 0, 0, 0);
    }
}

// ---------------------------------------------------------------------------
// Fused: ONE barrier-free GEMM mega-phase (4 internal-wx tiles + leaf GEMM),
// then climb d9..d4. LDS 144KB dedicated regions; climb reuses dead ones.
//   [0,16K)   FINT  -> H9 (after G)
//   [16,32K)  FLS   -> C9v
//   [32,96K)  BNC 64 slots -> H8,C8,H7,C7,H6,C6,H5,C5
//   [96,112K) HA
//   [112,144K) CA
// c workspace: d4 rows only, c[blockIdx*128 + col].
__global__ __launch_bounds__(512, 1) void fused6_k(const float* __restrict__ F,
                                                   const uint16_t* __restrict__ WT,
                                                   const float* __restrict__ biasS,
                                                   const uint16_t* __restrict__ UT,
                                                   float* __restrict__ h,
                                                   float* __restrict__ c) {
    __shared__ __align__(16) char SM[147456];
    uint16_t* FINT = (uint16_t*)SM;
    uint16_t* FLS  = (uint16_t*)(SM + 16384);
    uint16_t* BNC  = (uint16_t*)(SM + 32768);
    uint16_t* HA   = (uint16_t*)(SM + 98304);
    float*    CA   = (float*)(SM + 114688);
    uint16_t* H9   = (uint16_t*)SM;               // FINT dead after G
    float*    C9v  = (float*)(SM + 16384);        // FLS dead after G
    uint16_t* H8   = (uint16_t*)(SM + 32768);     // BNC dead after bnc_rd
    float*    C8   = (float*)(SM + 40960);
    uint16_t* H7   = (uint16_t*)(SM + 49152);
    float*    C7   = (float*)(SM + 57344);
    uint16_t* H6   = (uint16_t*)(SM + 65536);
    float*    C6   = (float*)(SM + 73728);
    uint16_t* H5   = (uint16_t*)(SM + 81920);
    float*    C5   = (float*)(SM + 90112);

    const int tid = threadIdx.x;
    const int w = tid >> 6, lane = tid & 63, q = lane >> 4, l15 = lane & 15;
    const int colf = w * 16 + l15;
    const int colb = w * 16 + q * 4;
    const int tree = blockIdx.x >> 4;
    const int pos4 = blockIdx.x & 15;
    const int vbase = tree * MTREE;
    const int v4 = vbase + 15 + pos4;
    const int v5 = vbase + 31 + 2 * pos4;
    const int v6 = vbase + 63 + 4 * pos4;
    const int v7 = vbase + 127 + 8 * pos4;
    const int v8 = vbase + 255 + 16 * pos4;
    const int v9 = vbase + 511 + 32 * pos4;
    const int vL = vbase + 1023 + 64 * pos4;

    // FINT row -> global node (rows 0..63; slot == row)
    auto fint_node = [&](int row) -> int {
        if (row < 32) return v9 + row;
        if (row < 48) return v8 + row - 32;
        if (row < 56) return v7 + row - 48;
        if (row < 60) return v6 + row - 56;
        if (row < 62) return v5 + row - 60;
        return v4;                       // rows 62,63 (63 = dummy dup)
    };

    // (1) issue FINT global loads
    const int srow = tid >> 4, scx = tid & 15;
    float4 i0[2], i1[2];
#pragma unroll
    for (int t = 0; t < 2; ++t) {
        int ci = t * 512 + tid;
        int row = ci >> 4, cx = ci & 15;
        const float* src = F + (size_t)fint_node(row) * 128 + cx * 8;
        i0[t] = *(const float4*)src;
        i1[t] = *(const float4*)(src + 4);
    }
    // (2) issue leaf F loads
    const float* sa = F + (size_t)(vL + srow) * 128 + scx * 8;
    const float* sb = F + (size_t)(vL + 32 + srow) * 128 + scx * 8;
    float4 a0 = *(const float4*)sa, a1 = *(const float4*)(sa + 4);
    float4 b0 = *(const float4*)sb, b1 = *(const float4*)(sb + 4);

    // (3) W weights + bias (L2-warm)
    bf16x8 aW[4][4];
    float4 bias4[4];
#pragma unroll
    for (int s = 0; s < 4; ++s) {
        int row = (w + s * 8) * 16 + l15;
#pragma unroll
        for (int kc = 0; kc < 4; ++kc)
            aW[s][kc] = *(const bf16x8*)(WT + (size_t)row * 128 + kc * 32 + q * 8);
        bias4[s] = *(const float4*)(biasS + (w + s * 8) * 16 + q * 4);
    }

    // (4) pack FINT + FLS -> LDS (dedicated regions)
#pragma unroll
    for (int t = 0; t < 2; ++t) {
        int ci = t * 512 + tid;
        int row = ci >> 4, cx = ci & 15;
        *(uint4*)&FINT[SWZ(row, cx)] = pack_bf8(i0[t], i1[t]);
    }
    *(uint4*)&FLS[SWZ(srow, scx)]      = pack_bf8(a0, a1);
    *(uint4*)&FLS[SWZ(32 + srow, scx)] = pack_bf8(b0, b1);
    lds_barrier();                                     // BAR 1

    // ---- G: barrier-free GEMM mega-phase (128 MFMAs) ----
    auto wx_tile = [&](int baseRow) {
        bf16x8 b[4];
#pragma unroll
        for (int kc = 0; kc < 4; ++kc)
            b[kc] = *(const bf16x8*)&FINT[SWZ(baseRow + l15, kc * 4 + q)];
        f32x4 acc[4] = {};
#pragma unroll
        for (int s = 0; s < 4; ++s)
#pragma unroll
            for (int kc = 0; kc < 4; ++kc)
                acc[s] = __builtin_amdgcn_mfma_f32_16x16x32_bf16(aW[s][kc], b[kc], acc[s], 0, 0, 0);
        int n = baseRow + l15;
#pragma unroll
        for (int r = 0; r < 4; ++r) {
            uint2 g;
            g.x = cvtpk(acc[0][r] + bias4[0][r], acc[1][r] + bias4[1][r]);
            g.y = cvtpk(acc[2][r] + bias4[2][r], acc[3][r] + bias4[3][r]);
            int f = colb + r;
            *(uint2*)&BNC[n * 512 + ((f ^ (n & 15)) << 2)] = g;
        }
    };
    wx_tile(0);
    wx_tile(16);
    wx_tile(32);
    wx_tile(48);

    // leaf GEMM + leaf epilogue (outputs to dedicated HA/CA)
#pragma unroll
    for (int nt = 0; nt < 4; ++nt) {
        bf16x8 b[4];
#pragma unroll
        for (int kc = 0; kc < 4; ++kc)
            b[kc] = *(const bf16x8*)&FLS[SWZ(nt * 16 + l15, kc * 4 + q)];
        f32x4 acc[4] = {};
#pragma unroll
        for (int s = 0; s < 4; ++s)
#pragma unroll
            for (int kc = 0; kc < 4; ++kc)
                acc[s] = __builtin_amdgcn_mfma_f32_16x16x32_bf16(aW[s][kc], b[kc], acc[s], 0, 0, 0);

        int row = nt * 16 + l15;
        float cv[4], hv[4];
#pragma unroll
        for (int r = 0; r < 4; ++r) {
            float pi = acc[0][r] + bias4[0][r];
            float po = acc[1][r] + bias4[1][r];
            float pu = acc[2][r] + bias4[2][r];
            float cn = sigmoidf_(pi) * tanhf_(pu);
            cv[r] = cn;
            hv[r] = sigmoidf_(po) * tanhf_(cn);
        }
        *(float4*)&h[(size_t)(vL + row) * 128 + colb] = *(float4*)hv;
        int chunk = colb >> 3, within = colb & 7;
        uint2 hp;
        hp.x = cvtpk(hv[0], hv[1]);
        hp.y = cvtpk(hv[2], hv[3]);
        *(uint2*)&HA[row * 128 + ((chunk ^ (row & 7)) * 8) + within] = hp;
        *(float4*)&CA[CAX(row, colb)] = *(float4*)cv;
    }
    bf16x8 bU[4][4];
    load_bU(UT, bU);    // after aW's last use
    lds_barrier();                                     // BAR 2

    // ---- read all wx from bounce into regs (BNC dead after this phase) ----
    auto bnc_rd = [&](int n, float o[4]) {
        wx_unpack(*(const ushort4*)&BNC[n * 512 + ((colf ^ (n & 15)) << 2)], o);
    };
    float wxA[4][2][4], wxB[2][2][4], wxC[2][4], wxD[2][4], wxE[2][4], wxFp[2][4];
#pragma unroll
    for (int ct = 0; ct < 4; ++ct)
#pragma unroll
        for (int j = 0; j < 2; ++j)
            bnc_rd(ct * 8 + q * 2 + j, wxA[ct][j]);
#pragma unroll
    for (int ct = 0; ct < 2; ++ct)
#pragma unroll
        for (int j = 0; j < 2; ++j)
            bnc_rd(32 + ct * 8 + q * 2 + j, wxB[ct][j]);
#pragma unroll
    for (int j = 0; j < 2; ++j) {
        int pl = q * 2 + j;
        bnc_rd(48 + pl, wxC[j]);
        bnc_rd(56 + (pl & 3), wxD[j]);
        bnc_rd(60 + (pl & 1), wxE[j]);
        bnc_rd(62, wxFp[j]);
    }

    // ---- LEVEL A (d9): 32 parents from 64 leaf children ----
    {
        f32x4 acc[4][4] = {};
        matvec_lds<4>(HA, bU, acc, l15, q);
#pragma unroll
        for (int ct = 0; ct < 4; ++ct) {
            float cch[4];
#pragma unroll
            for (int r = 0; r < 4; ++r)
                cch[r] = CA[CAX(ct * 16 + q * 4 + r, colf)];
            float hv[2], cn[2];
            gate_epi(acc[ct], wxA[ct], cch, hv, cn);
#pragma unroll
            for (int j = 0; j < 2; ++j) {
                int pl = ct * 8 + q * 2 + j;
                h[(size_t)(v9 + pl) * 128 + colf] = hv[j];
                hwr(H9, pl, colf, hv[j]);
                C9v[CIDX(pl, colf)] = cn[j];
            }
        }
    }
    lds_barrier();                                     // BAR 3

    // ---- LEVEL B (d8): 16 parents ----
    {
        float cch[2][4];
#pragma unroll
        for (int ct = 0; ct < 2; ++ct)
#pragma unroll
            for (int r = 0; r < 4; ++r)
                cch[ct][r] = C9v[CIDX(ct * 16 + q * 4 + r, colf)];
        f32x4 acc[2][4] = {};
        matvec_lds<2>(H9, bU, acc, l15, q);
#pragma unroll
        for (int ct = 0; ct < 2; ++ct) {
            float hv[2], cn[2];
            gate_epi(acc[ct], wxB[ct], cch[ct], hv, cn);
#pragma unroll
            for (int j = 0; j < 2; ++j) {
                int pl = ct * 8 + q * 2 + j;
                h[(size_t)(v8 + pl) * 128 + colf] = hv[j];
                hwr(H8, pl, colf, hv[j]);
                C8[CIDX(pl, colf)] = cn[j];
            }
        }
    }
    lds_barrier();                                     // BAR 4

    // ---- LEVEL C (d7): 8 parents ----
    {
        float cch[4];
#pragma unroll
        for (int r = 0; r < 4; ++r)
            cch[r] = C8[CIDX(q * 4 + r, colf)];
        f32x4 acc[1][4] = {};
        matvec_lds<1>(H8, bU, acc, l15, q);
        float hv[2], cn[2];
        gate_epi(acc[0], wxC, cch, hv, cn);
#pragma unroll
        for (int j = 0; j < 2; ++j) {
            int pl = q * 2 + j;
            h[(size_t)(v7 + pl) * 128 + colf] = hv[j];
            hwr(H7, pl, colf, hv[j]);
            C7[CIDX(pl, colf)] = cn[j];
        }
    }
    lds_barrier();                                     // BAR 5

    // ---- LEVEL D (d6): 4 parents ----
    {
        float cch[4];
#pragma unroll
        for (int r = 0; r < 4; ++r)
            cch[r] = C7[CIDX(q * 4 + r, colf)];
        f32x4 acc[1][4] = {};
        matvec_lds<1>(H7, bU, acc, l15, q);
        float hv[2], cn[2];
        gate_epi(acc[0], wxD, cch, hv, cn);
#pragma unroll
        for (int j = 0; j < 2; ++j) {
            int pl = q * 2 + j;
            if (pl < 4) {
                h[(size_t)(v6 + pl) * 128 + colf] = hv[j];
                hwr(H6, pl, colf, hv[j]);
                C6[CIDX(pl, colf)] = cn[j];
            }
        }
    }
    lds_barrier();                                     // BAR 6

    // ---- LEVEL E (d5): 2 parents ----
    {
        float cch[4];
#pragma unroll
        for (int r = 0; r < 4; ++r)
            cch[r] = C6[CIDX(q * 4 + r, colf)];
        f32x4 acc[1][4] = {};
        matvec_lds<1>(H6, bU, acc, l15, q);
        float hv[2], cn[2];
        gate_epi(acc[0], wxE, cch, hv, cn);
#pragma unroll
        for (int j = 0; j < 2; ++j) {
            int pl = q * 2 + j;
            if (pl < 2) {
                h[(size_t)(v5 + pl) * 128 + colf] = hv[j];
                hwr(H5, pl, colf, hv[j]);
                C5[CIDX(pl, colf)] = cn[j];
            }
        }
    }
    lds_barrier();                                     // BAR 7

    // ---- LEVEL F (d4): 1 parent -> global h + compact c (tail handoff) ----
    {
        float cch[4];
#pragma unroll
        for (int r = 0; r < 4; ++r)
            cch[r] = C5[CIDX(q * 4 + r, colf)];
        f32x4 acc[1][4] = {};
        matvec_lds<1>(H5, bU, acc, l15, q);
        float hv[2], cn[2];
        gate_epi(acc[0], wxFp, cch, hv, cn);
        if (q == 0) {
            h[(size_t)v4 * 128 + colf] = hv[0];
            c[(size_t)blockIdx.x * 128 + colf] = cn[0];   // compact d4 c
        }
    }
}

// ---------------------------------------------------------------------------
// Tail: self-computed wx for d3..d0 (15 nodes), then climb. 1 block/tree.
// c read is compact: c[tree*16 + k] = d4 node k of tree.
__global__ __launch_bounds__(512, 1) void tail_k(const float* __restrict__ F,
                                                 const uint16_t* __restrict__ WT,
                                                 const float* __restrict__ biasS,
                                                 const uint16_t* __restrict__ UT,
                                                 const float* __restrict__ cglob,
                                                 float* __restrict__ h) {
    __shared__ __align__(16) char SMt[29184];
    uint16_t* Hbuf  = (uint16_t*)SMt;
    float*    CS    = (float*)(SMt + 12288);
    uint16_t* FINTt = (uint16_t*)SMt;
    uint16_t* BNCt  = (uint16_t*)(SMt + 4096);

    const int tid = threadIdx.x;
    const int w = tid >> 6, lane = tid & 63, q = lane >> 4, l15 = lane & 15;
    const int colf = w * 16 + l15;
    const int colb = w * 16 + q * 4;
    const int tree = blockIdx.x;
    const int vb = tree * MTREE;

    // FINTt row -> node: 0-7 d3(j=7..14), 8-11 d2(j=3..6), 12-13 d1, 14 d0
    auto tnode = [&](int row) -> int {
        if (row < 8) return vb + 7 + row;
        if (row < 12) return vb + 3 + (row - 8);
        if (row < 14) return vb + 1 + (row - 12);
        return vb;
    };

    // (1) issue global loads: internal F rows, d4 h rows, compact d4 c
    float4 fi0, fi1, hh0, hh1;
    if (tid < 256) {
        int row = tid >> 4, cx = tid & 15;
        const float* fsrc = F + (size_t)tnode(row) * 128 + cx * 8;
        fi0 = *(const float4*)fsrc;
        fi1 = *(const float4*)(fsrc + 4);
        const float* hsrc = h + (size_t)(vb + 15 + row) * 128 + cx * 8;
        hh0 = *(const float4*)hsrc;
        hh1 = *(const float4*)(hsrc + 4);
    }
    float cgl[4];
#pragma unroll
    for (int r = 0; r < 4; ++r) {
        int cl = q * 4 + r;
        cgl[r] = cglob[(size_t)(tree * 16 + cl) * 128 + colf];
    }

    // (2) weights (L2-warm)
    bf16x8 aW[4][4];
    float4 bias4[4];
#pragma unroll
    for (int s = 0; s < 4; ++s) {
        int row = (w + s * 8) * 16 + l15;
#pragma unroll
        for (int kc = 0; kc < 4; ++kc)
            aW[s][kc] = *(const bf16x8*)(WT + (size_t)row * 128 + kc * 32 + q * 8);
        bias4[s] = *(const float4*)(biasS + (w + s * 8) * 16 + q * 4);
    }
    bf16x8 bU[4][4];
    load_bU(UT, bU);

    // (3) pack FINTt
    if (tid < 256) {
        int row = tid >> 4, cx = tid & 15;
        *(uint4*)&FINTt[SWZ(row, cx)] = pack_bf8(fi0, fi1);
    }
    lds_barrier();

    // ---- phase W: one GEMM tile -> bounce ----
    {
        bf16x8 b[4];
#pragma unroll
        for (int kc = 0; kc < 4; ++kc)
            b[kc] = *(const bf16x8*)&FINTt[SWZ(l15, kc * 4 + q)];
        f32x4 acc[4] = {};
#pragma unroll
        for (int s = 0; s < 4; ++s)
#pragma unroll
            for (int kc = 0; kc < 4; ++kc)
                acc[s] = __builtin_amdgcn_mfma_f32_16x16x32_bf16(aW[s][kc], b[kc], acc[s], 0, 0, 0);
        int n = l15;
#pragma unroll
        for (int r = 0; r < 4; ++r) {
            uint2 g;
            g.x = cvtpk(acc[0][r] + bias4[0][r], acc[1][r] + bias4[1][r]);
            g.y = cvtpk(acc[2][r] + bias4[2][r], acc[3][r] + bias4[3][r]);
            int f = colb + r;
            *(uint2*)&BNCt[n * 512 + ((f ^ (n & 15)) << 2)] = g;
        }
    }
    lds_barrier();

    float wx1[2][4], wx2[2][4], wx3[2][4], wx4p[2][4];
#pragma unroll
    for (int j = 0; j < 2; ++j) {
        int pl = q * 2 + j;
        wx_unpack(*(const ushort4*)&BNCt[pl * 512 + ((colf ^ (pl & 15)) << 2)], wx1[j]);
        int n2 = 8 + (pl & 3);
        wx_unpack(*(const ushort4*)&BNCt[n2 * 512 + ((colf ^ (n2 & 15)) << 2)], wx2[j]);
        int n3 = 12 + (pl & 1);
        wx_unpack(*(const ushort4*)&BNCt[n3 * 512 + ((colf ^ (n3 & 15)) << 2)], wx3[j]);
        wx_unpack(*(const ushort4*)&BNCt[14 * 512 + ((colf ^ 14) << 2)], wx4p[j]);
    }
    lds_barrier();   // BNCt dead

    // (4) pack d4 h -> Hbuf rows 0..15
    if (tid < 256) {
        int row = tid >> 4, cx = tid & 15;
        *(uint4*)&Hbuf[SWZ(row, cx)] = pack_bf8(hh0, hh1);
    }
    lds_barrier();

    // ---- G1: d3, 8 parents ----
    {
        f32x4 acc[1][4] = {};
        matvec_lds<1>(Hbuf, bU, acc, l15, q);
        float hv[2], cn[2];
        gate_epi(acc[0], wx1, cgl, hv, cn);
#pragma unroll
        for (int j = 0; j < 2; ++j) {
            int pl = q * 2 + j;
            h[(size_t)(vb + 7 + pl) * 128 + colf] = hv[j];
            hwr(Hbuf, 16 + pl, colf, hv[j]);
            CS[pl * 132 + colf] = cn[j];
        }
    }
    lds_barrier();

    // ---- G2: d2, 4 parents ----
    {
        float cch[4];
#pragma unroll
        for (int r = 0; r < 4; ++r)
            cch[r] = CS[(q * 4 + r) * 132 + colf];
        f32x4 acc[1][4] = {};
        matvec_lds<1>(&Hbuf[16 * 128], bU, acc, l15, q);
        float hv[2], cn[2];
        gate_epi(acc[0], wx2, cch, hv, cn);
#pragma unroll
        for (int j = 0; j < 2; ++j) {
            int pl = q * 2 + j;
            if (pl < 4) {
                h[(size_t)(vb + 3 + pl) * 128 + colf] = hv[j];
                hwr(Hbuf, 32 + pl, colf, hv[j]);
                CS[(16 + pl) * 132 + colf] = cn[j];
            }
        }
    }
    lds_barrier();

    // ---- G3: d1, 2 parents ----
    {
        float cch[4];
#pragma unroll
        for (int r = 0; r < 4; ++r)
            cch[r] = CS[(16 + q * 4 + r) * 132 + colf];
        f32x4 acc[1][4] = {};
        matvec_lds<1>(&Hbuf[32 * 128], bU, acc, l15, q);
        float hv[2], cn[2];
        gate_epi(acc[0], wx3, cch, hv, cn);
#pragma unroll
        for (int j = 0; j < 2; ++j) {
            int pl = q * 2 + j;
            if (pl < 2) {
                h[(size_t)(vb + 1 + pl) * 128 + colf] = hv[j];
                hwr(Hbuf, 40 + pl, colf, hv[j]);
                CS[pl * 132 + colf] = cn[j];
            }
        }
    }
    lds_barrier();

    // ---- G4: d0, root ----
    {
        float cch[4];
#pragma unroll
        for (int r = 0; r < 4; ++r)
            cch[r] = CS[(q * 4 + r) * 132 + colf];
        f32x4 acc[1][4] = {};
        matvec_lds<1>(&Hbuf[40 * 128], bU, acc, l15, q);
        float hv[2], cn[2];
        gate_epi(acc[0], wx4p, cch, hv, cn);
        if (q == 0) {
            h[(size_t)vb * 128 + colf] = hv[0];
        }
    }
}

// ---------------------------------------------------------------------------
extern "C" void kernel_launch(void* const* d_in, const int* in_sizes, int n_in,
                              void* d_out, int out_size, void* d_ws, size_t ws_size,
                              hipStream_t stream) {
    const float* features = (const float*)d_in[0];
    const float* W_iou    = (const float*)d_in[1];
    const float* b_iou    = (const float*)d_in[2];
    const float* U_iou    = (const float*)d_in[3];
    const float* W_f      = (const float*)d_in[4];
    const float* b_f      = (const float*)d_in[5];
    const float* U_f      = (const float*)d_in[6];
    float* h = (float*)d_out;

    char* wp = (char*)d_ws;
    float*    c     = (float*)wp;    wp += 512 * 128 * 4;      // d4 rows only
    uint16_t* WT    = (uint16_t*)wp; wp += 512 * 128 * 2;
    uint16_t* UT    = (uint16_t*)wp; wp += 512 * 128 * 2;
    float*    biasS = (float*)wp;    wp += 512 * 4;

    hipLaunchKernelGGL(prep_k, dim3(1025), dim3(128), 0, stream,
                       W_iou, W_f, U_iou, U_f, b_iou, b_f, WT, UT, biasS);
    hipLaunchKernelGGL(fused6_k, dim3(512), dim3(512), 0, stream,
                       features, WT, biasS, UT, h, c);
    hipLaunchKernelGGL(tail_k, dim3(32), dim3(512), 0, stream,
                       features, WT, biasS, UT, c, h);
}